// Round 8
// baseline (959.227 us; speedup 1.0000x reference)
//
#include <hip/hip_runtime.h>
#include <stdint.h>

#define NNODES  200000
#define NEDGES  400000
#define NE2     (NEDGES + NNODES)   // edges + self-loops in CSR
#define NGRAPHS 4000
#define NLAYERS 5
#define BN_EPS  1e-5f
#define INV_N   (1.0f / (float)NNODES)

typedef __attribute__((ext_vector_type(8))) short short8;
typedef __attribute__((ext_vector_type(4))) float f32x4;

__device__ __forceinline__ unsigned int f2bf(float f) {
    unsigned int u = __float_as_uint(f);
    return (u + 0x7fffu + ((u >> 16) & 1u)) >> 16;
}
__device__ __forceinline__ float bf2f(unsigned int b) {
    return __uint_as_float(b << 16);
}

__device__ __forceinline__ void acc8(float (&a)[8], float wgt, const uint4& g) {
    a[0] = fmaf(wgt, bf2f(g.x & 0xffffu), a[0]);
    a[1] = fmaf(wgt, bf2f(g.x >> 16),     a[1]);
    a[2] = fmaf(wgt, bf2f(g.y & 0xffffu), a[2]);
    a[3] = fmaf(wgt, bf2f(g.y >> 16),     a[3]);
    a[4] = fmaf(wgt, bf2f(g.z & 0xffffu), a[4]);
    a[5] = fmaf(wgt, bf2f(g.z >> 16),     a[5]);
    a[6] = fmaf(wgt, bf2f(g.w & 0xffffu), a[6]);
    a[7] = fmaf(wgt, bf2f(g.w >> 16),     a[7]);
}

// ---------------- graph prep ----------------

__global__ void k_init(int* __restrict__ cnt, int* __restrict__ cursor,
                       float* __restrict__ stats, int2* __restrict__ cedge_tail) {
    int i = blockIdx.x * 256 + threadIdx.x;
    if (i < NNODES) { cnt[i] = 0; cursor[i] = 0; }
    if (i < NLAYERS * 256) stats[i] = 0.f;
    if (i < 4) { int2 z; z.x = 0; z.y = 0; cedge_tail[i] = z; }  // zero CSR pad
}

__global__ void k_count(const int* __restrict__ ei, int* __restrict__ cnt) {
    int e = blockIdx.x * 256 + threadIdx.x;
    if (e < NEDGES) atomicAdd(&cnt[ei[NEDGES + e]], 1);
}

// block-scan of (cnt[v]+1) [self-loop included]; also graph ranges from sorted batch
__global__ __launch_bounds__(256) void k_scan1(const int* __restrict__ cnt,
                                               int* __restrict__ roff, int* __restrict__ bsum,
                                               const int* __restrict__ batch,
                                               int* __restrict__ gstart) {
    __shared__ int s[256];
    int t = threadIdx.x;
    int v = blockIdx.x * 256 + t;
    int val = (v < NNODES) ? cnt[v] + 1 : 0;
    s[t] = val; __syncthreads();
    int sum = val;
    for (int o = 1; o < 256; o <<= 1) {
        int tmp = (t >= o) ? s[t - o] : 0;
        __syncthreads();
        sum += tmp; s[t] = sum;
        __syncthreads();
    }
    if (v < NNODES) roff[v] = sum - val;       // exclusive within block
    if (t == 255) bsum[blockIdx.x] = s[255];

    if (v < NNODES) {   // graph ranges (merged k_ranges)
        int b = batch[v];
        if (v == 0) {
            for (int g = 0; g <= b; ++g) gstart[g] = 0;
        } else {
            int pb = batch[v - 1];
            for (int g = pb + 1; g <= b; ++g) gstart[g] = v;
        }
        if (v == NNODES - 1) {
            for (int g = b + 1; g <= NGRAPHS; ++g) gstart[g] = NNODES;
        }
    }
}

__global__ __launch_bounds__(1024) void k_scan2(int* __restrict__ bsum, int nb) {
    __shared__ int s[1024];
    int t = threadIdx.x;
    int val = (t < nb) ? bsum[t] : 0;
    s[t] = val; __syncthreads();
    int sum = val;
    for (int o = 1; o < 1024; o <<= 1) {
        int tmp = (t >= o) ? s[t - o] : 0;
        __syncthreads();
        sum += tmp; s[t] = sum;
        __syncthreads();
    }
    if (t < nb) bsum[t] = sum - val;           // exclusive block offsets
}

// finalize roff; compute dinv; write the self-loop edge at slot roff[v]
__global__ void k_scan3(int* __restrict__ roff, const int* __restrict__ bsum,
                        const int* __restrict__ cnt, float* __restrict__ dinv,
                        int2* __restrict__ cedge) {
    int v = blockIdx.x * 256 + threadIdx.x;
    if (v < NNODES) {
        int r = roff[v] + bsum[blockIdx.x];
        roff[v] = r;
        float dv = rsqrtf((float)cnt[v] + 1.0f);
        dinv[v] = dv;
        int2 se; se.x = v; se.y = __float_as_int(dv * dv);
        cedge[r] = se;
    }
    if (v == 0) roff[NNODES] = NE2;
}

// real edges go to slots roff[d]+1+pos (slot 0 is the self-loop)
__global__ void k_fill(const int* __restrict__ ei, const float* __restrict__ dinv,
                       const int* __restrict__ roff, int* __restrict__ cursor,
                       int2* __restrict__ cedge) {
    int e = blockIdx.x * 256 + threadIdx.x;
    if (e >= NEDGES) return;
    int s = ei[e], d = ei[NEDGES + e];
    int pos = atomicAdd(&cursor[d], 1);
    int idx = roff[d] + 1 + pos;
    int2 ed; ed.x = s; ed.y = __float_as_int(dinv[s] * dinv[d]);
    cedge[idx] = ed;
}

// transpose + bf16-convert + swizzle layer weights WT[n][k]=W[k][n] (256B rows),
// and Wx -> WxT[n][k0..63] zero-padded (128B rows), with bias folded at k=40.
__global__ void k_wtrans(const float* __restrict__ Wg, const float* __restrict__ Wx,
                         const float* __restrict__ bx,
                         char* __restrict__ wt, char* __restrict__ wxt) {
    int idx = blockIdx.x * 256 + threadIdx.x;
    if (idx < NLAYERS * 16384) {
        int l = idx >> 14;
        int rem = idx & 16383;
        int n = rem >> 7;
        int k = rem & 127;
        float v = Wg[l * 16384 + k * 128 + n];
        char* img = wt + l * 32768;
        *(unsigned short*)(img + (n << 8) + ((k << 1) ^ ((n & 7) << 4))) = (unsigned short)f2bf(v);
    } else if (idx < NLAYERS * 16384 + 8192) {
        int j = idx - NLAYERS * 16384;
        int n = j >> 6;
        int k = j & 63;
        float v = (k < 40) ? Wx[k * 128 + n] : (k == 40 ? bx[n] : 0.f);
        *(unsigned short*)(wxt + (n << 7) + ((k << 1) ^ ((n & 7) << 4))) = (unsigned short)f2bf(v);
    }
}

// ---------------- input projection (MFMA): h0 = bf16(x @ Wx + bx) ----------------

__global__ __launch_bounds__(256) void k_inproj(const float* __restrict__ x,
                                                const char* __restrict__ wxt,
                                                unsigned short* __restrict__ out) {
    __shared__ char As[16384];   // 128 rows * 128 B
    const int tid = threadIdx.x;
    const int m0 = blockIdx.x << 7;

    { // stage A: 16 threads per row cover k 0..63 (4 each); k=40 -> 1.0
        const int kq = (tid & 15) << 2;   // 0,4,...,60
        const int r0 = tid >> 4;          // 0..15
        #pragma unroll
        for (int it = 0; it < 8; ++it) {
            const int r = r0 + (it << 4);
            const int grow = m0 + r;
            float x0 = 0.f, x1 = 0.f, x2 = 0.f, x3 = 0.f;
            if (grow < NNODES) {
                if (kq < 40) {
                    const float4 v = *(const float4*)(x + (size_t)grow * 40 + kq);
                    x0 = v.x; x1 = v.y; x2 = v.z; x3 = v.w;
                } else if (kq == 40) {
                    x0 = 1.0f;   // homogeneous coordinate -> bias via MFMA
                }
            }
            uint2 p;
            p.x = f2bf(x0) | (f2bf(x1) << 16);
            p.y = f2bf(x2) | (f2bf(x3) << 16);
            *(uint2*)(As + (r << 7) + ((kq << 1) ^ ((r & 7) << 4))) = p;
        }
    }
    __syncthreads();

    const int lane = tid & 63;
    const int wid = tid >> 6;
    const int l15 = lane & 15;
    const int lq = lane >> 4;

    const f32x4 zero = {0.f, 0.f, 0.f, 0.f};
    f32x4 acc[2][8];
    #pragma unroll
    for (int i = 0; i < 2; ++i)
        #pragma unroll
        for (int j = 0; j < 8; ++j) acc[i][j] = zero;

    #pragma unroll
    for (int kk = 0; kk < 2; ++kk) {
        const int kb = (kk << 6) + (lq << 4);
        short8 afr[2];
        #pragma unroll
        for (int rt = 0; rt < 2; ++rt) {
            const int r = (wid << 5) + (rt << 4) + l15;
            afr[rt] = *(const short8*)(As + (r << 7) + (kb ^ ((r & 7) << 4)));
        }
        #pragma unroll
        for (int ct = 0; ct < 8; ++ct) {
            const int n = (ct << 4) + l15;
            const short8 bfr = *(const short8*)(wxt + (n << 7) + (kb ^ ((n & 7) << 4)));
            acc[0][ct] = __builtin_amdgcn_mfma_f32_16x16x32_bf16(bfr, afr[0], acc[0][ct], 0, 0, 0);
            acc[1][ct] = __builtin_amdgcn_mfma_f32_16x16x32_bf16(bfr, afr[1], acc[1][ct], 0, 0, 0);
        }
    }

    #pragma unroll
    for (int rt = 0; rt < 2; ++rt) {
        const int grow = m0 + (wid << 5) + (rt << 4) + l15;   // node
        if (grow < NNODES) {
            #pragma unroll
            for (int ct = 0; ct < 8; ++ct) {
                uint2 pk;
                pk.x = f2bf(acc[rt][ct][0]) | (f2bf(acc[rt][ct][1]) << 16);
                pk.y = f2bf(acc[rt][ct][2]) | (f2bf(acc[rt][ct][3]) << 16);
                *(uint2*)(out + (size_t)grow * 128 + (ct << 4) + (lq << 2)) = pk;
            }
        }
    }
}

// ---------------- per-layer GEMM: xw(bf16) = BNrelu(in_bf16) @ Wg[l] ----------------
// B staged to LDS via global_load_lds (issued first, lands during A-stage);
// BN coefficients computed inline from raw stats (no bnfin kernel).

__global__ __launch_bounds__(256) void k_gemm(const unsigned short* __restrict__ in,
                                              const char* __restrict__ wt,
                                              unsigned short* __restrict__ out,
                                              const float* __restrict__ statsPrev,
                                              const float* __restrict__ gamma,
                                              const float* __restrict__ beta,
                                              int apply_bn) {
    __shared__ char As[32768];   // A tile, swizzled 256B rows
    __shared__ char Bs[32768];   // W^T image copy

    const int tid = threadIdx.x;
    const int lane = tid & 63;
    const int wid = tid >> 6;
    const int m0 = blockIdx.x << 7;

    { // issue B staging first: 32 chunks of 1KB, wave-linear global_load_lds
        #pragma unroll
        for (int i = 0; i < 8; ++i) {
            const int chunk = ((i << 2) + wid) << 10;   // (i*4 + wave) * 1024
            __builtin_amdgcn_global_load_lds(
                (const __attribute__((address_space(1))) unsigned int*)(wt + chunk + (lane << 4)),
                (__attribute__((address_space(3))) unsigned int*)(Bs + chunk),
                16, 0, 0);
        }
    }
    { // stage A: load bf16, BN+relu in fp32, back to bf16, swizzled ds_write
        const int c0 = (tid & 31) << 2;
        float scv[4] = {1.f, 1.f, 1.f, 1.f};
        float shv[4] = {0.f, 0.f, 0.f, 0.f};
        if (apply_bn) {
            #pragma unroll
            for (int j = 0; j < 4; ++j) {
                const float m = statsPrev[c0 + j] * INV_N;
                const float var = statsPrev[128 + c0 + j] * INV_N - m * m;
                const float s = gamma[c0 + j] * rsqrtf(var + BN_EPS);
                scv[j] = s;
                shv[j] = fmaf(-m, s, beta[c0 + j]);
            }
        }
        const int r0 = tid >> 5;
        #pragma unroll
        for (int it = 0; it < 16; ++it) {
            const int r = r0 + (it << 3);
            const int grow = m0 + r;
            uint2 p = {0u, 0u};
            if (grow < NNODES) {
                const uint2 raw = *(const uint2*)(in + (size_t)grow * 128 + c0);
                if (apply_bn) {
                    float x0 = fmaxf(fmaf(bf2f(raw.x & 0xffffu), scv[0], shv[0]), 0.f);
                    float x1 = fmaxf(fmaf(bf2f(raw.x >> 16),     scv[1], shv[1]), 0.f);
                    float x2 = fmaxf(fmaf(bf2f(raw.y & 0xffffu), scv[2], shv[2]), 0.f);
                    float x3 = fmaxf(fmaf(bf2f(raw.y >> 16),     scv[3], shv[3]), 0.f);
                    p.x = f2bf(x0) | (f2bf(x1) << 16);
                    p.y = f2bf(x2) | (f2bf(x3) << 16);
                } else {
                    p = raw;   // already bf16
                }
            }
            *(uint2*)(As + (r << 8) + ((c0 << 1) ^ ((r & 7) << 4))) = p;
        }
    }
    __syncthreads();   // drains vmcnt -> Bs ready too

    const int l15 = lane & 15;
    const int lq = lane >> 4;

    const f32x4 zero = {0.f, 0.f, 0.f, 0.f};
    f32x4 acc[2][8];
    #pragma unroll
    for (int i = 0; i < 2; ++i)
        #pragma unroll
        for (int j = 0; j < 8; ++j) acc[i][j] = zero;

    #pragma unroll
    for (int kk = 0; kk < 4; ++kk) {
        const int kb = (kk << 6) + (lq << 4);
        short8 afr[2];
        #pragma unroll
        for (int rt = 0; rt < 2; ++rt) {
            const int r = (wid << 5) + (rt << 4) + l15;
            afr[rt] = *(const short8*)(As + (r << 8) + (kb ^ ((r & 7) << 4)));
        }
        #pragma unroll
        for (int ct = 0; ct < 8; ++ct) {
            const int n = (ct << 4) + l15;
            const short8 bfr = *(const short8*)(Bs + (n << 8) + (kb ^ ((n & 7) << 4)));
            // swapped operands: D[channel][node]
            acc[0][ct] = __builtin_amdgcn_mfma_f32_16x16x32_bf16(bfr, afr[0], acc[0][ct], 0, 0, 0);
            acc[1][ct] = __builtin_amdgcn_mfma_f32_16x16x32_bf16(bfr, afr[1], acc[1][ct], 0, 0, 0);
        }
    }

    #pragma unroll
    for (int rt = 0; rt < 2; ++rt) {
        const int grow = m0 + (wid << 5) + (rt << 4) + l15;   // node
        if (grow < NNODES) {
            #pragma unroll
            for (int ct = 0; ct < 8; ++ct) {
                uint2 pk;
                pk.x = f2bf(acc[rt][ct][0]) | (f2bf(acc[rt][ct][1]) << 16);
                pk.y = f2bf(acc[rt][ct][2]) | (f2bf(acc[rt][ct][3]) << 16);
                *(uint2*)(out + (size_t)grow * 128 + (ct << 4) + (lq << 2)) = pk;
            }
        }
    }
}

// ------- aggregation: agg_l = bg + BNrelu(prev) + sum over CSR(self included) -------
// 4 nodes/wave (16 lanes x 8ch); batch-4 edges (2 x uint4 metadata loads, 4 gathers
// in flight per slot); cross-sweep prefetch of roff(uint2) + residual row.

__global__ __launch_bounds__(256) void k_agg(const unsigned short* __restrict__ prev,
                                             const unsigned short* __restrict__ xw,
                                             const int* __restrict__ roff,
                                             const int2* __restrict__ cedge,
                                             const float* __restrict__ bg,
                                             const float* __restrict__ statsPrev,
                                             const float* __restrict__ gamma,
                                             const float* __restrict__ beta,
                                             int apply_bn,
                                             unsigned short* __restrict__ outb,
                                             float* __restrict__ statsOut) {
    const int lane = threadIdx.x & 63;
    const int wv   = threadIdx.x >> 6;       // wave 0..3
    const int g16  = lane >> 4;              // node slot within wave 0..3
    const int l16  = lane & 15;
    const int c8   = l16 << 3;               // channel base (8 channels per lane)

    float sc[8], sh[8], bgv[8];
    #pragma unroll
    for (int j = 0; j < 8; ++j) {
        if (apply_bn) {
            const float m = statsPrev[c8 + j] * INV_N;
            const float var = statsPrev[128 + c8 + j] * INV_N - m * m;
            const float s = gamma[c8 + j] * rsqrtf(var + BN_EPS);
            sc[j] = s;
            sh[j] = fmaf(-m, s, beta[c8 + j]);
        } else { sc[j] = 1.f; sh[j] = 0.f; }
        bgv[j] = bg[c8 + j];
    }
    float s_[8], q_[8];
    #pragma unroll
    for (int j = 0; j < 8; ++j) { s_[j] = 0.f; q_[j] = 0.f; }

    const int stride = gridDim.x * 16;
    int v = blockIdx.x * 16 + wv * 4 + g16;
    uint2 rof = {0u, 0u};
    uint4 resu = {0u, 0u, 0u, 0u};
    if (v < NNODES) {
        rof  = *(const uint2*)(roff + v);
        resu = *(const uint4*)(prev + (size_t)v * 128 + c8);
    }
    while (v < NNODES) {
        const int vn = v + stride;
        uint2 rofn = {0u, 0u};
        uint4 resn = {0u, 0u, 0u, 0u};
        if (vn < NNODES) {   // prefetch next sweep before the edge chain
            rofn = *(const uint2*)(roff + vn);
            resn = *(const uint4*)(prev + (size_t)vn * 128 + c8);
        }
        float a[8];
        {
            float r[8];
            r[0] = bf2f(resu.x & 0xffffu); r[1] = bf2f(resu.x >> 16);
            r[2] = bf2f(resu.y & 0xffffu); r[3] = bf2f(resu.y >> 16);
            r[4] = bf2f(resu.z & 0xffffu); r[5] = bf2f(resu.z >> 16);
            r[6] = bf2f(resu.w & 0xffffu); r[7] = bf2f(resu.w >> 16);
            if (apply_bn) {
                #pragma unroll
                for (int j = 0; j < 8; ++j)
                    a[j] = bgv[j] + fmaxf(fmaf(r[j], sc[j], sh[j]), 0.f);
            } else {
                #pragma unroll
                for (int j = 0; j < 8; ++j) a[j] = bgv[j] + r[j];
            }
        }
        int e = (int)rof.x;
        const int e1 = (int)rof.y;
        while (e < e1) {   // at least one edge (the self-loop)
            const int rem = e1 - e;
            const uint4 m01 = *(const uint4*)(cedge + e);       // edges e, e+1
            const uint4 m23 = *(const uint4*)(cedge + e + 2);   // edges e+2, e+3 (padded)
            const int src0 = (int)m01.x;
            const int src1 = rem > 1 ? (int)m01.z : src0;
            const int src2 = rem > 2 ? (int)m23.x : src0;
            const int src3 = rem > 3 ? (int)m23.z : src0;
            const float w0 = __uint_as_float(m01.y);
            const float w1 = rem > 1 ? __uint_as_float(m01.w) : 0.f;
            const float w2 = rem > 2 ? __uint_as_float(m23.y) : 0.f;
            const float w3 = rem > 3 ? __uint_as_float(m23.w) : 0.f;
            const uint4 g0 = *(const uint4*)(xw + (size_t)src0 * 128 + c8);
            const uint4 g1 = *(const uint4*)(xw + (size_t)src1 * 128 + c8);
            const uint4 g2 = *(const uint4*)(xw + (size_t)src2 * 128 + c8);
            const uint4 g3 = *(const uint4*)(xw + (size_t)src3 * 128 + c8);
            acc8(a, w0, g0);
            acc8(a, w1, g1);
            acc8(a, w2, g2);
            acc8(a, w3, g3);
            e += 4;
        }
        uint4 o;
        o.x = f2bf(a[0]) | (f2bf(a[1]) << 16);
        o.y = f2bf(a[2]) | (f2bf(a[3]) << 16);
        o.z = f2bf(a[4]) | (f2bf(a[5]) << 16);
        o.w = f2bf(a[6]) | (f2bf(a[7]) << 16);
        *(uint4*)(outb + (size_t)v * 128 + c8) = o;
        #pragma unroll
        for (int j = 0; j < 8; ++j) {
            s_[j] += a[j];
            q_[j] = fmaf(a[j], a[j], q_[j]);
        }
        v = vn; rof = rofn; resu = resn;
    }

    // combine the 4 node-slots (channels depend on l16 only)
    #pragma unroll
    for (int j = 0; j < 8; ++j) {
        s_[j] += __shfl_xor(s_[j], 16); s_[j] += __shfl_xor(s_[j], 32);
        q_[j] += __shfl_xor(q_[j], 16); q_[j] += __shfl_xor(q_[j], 32);
    }
    __shared__ float red[512];
    if (g16 == 0) {
        #pragma unroll
        for (int j = 0; j < 8; ++j) red[wv * 128 + c8 + j] = s_[j];
    }
    __syncthreads();
    if (threadIdx.x < 128) {
        const int ch = threadIdx.x;
        atomicAdd(&statsOut[ch], red[ch] + red[128 + ch] + red[256 + ch] + red[384 + ch]);
    }
    __syncthreads();
    if (g16 == 0) {
        #pragma unroll
        for (int j = 0; j < 8; ++j) red[wv * 128 + c8 + j] = q_[j];
    }
    __syncthreads();
    if (threadIdx.x < 128) {
        const int ch = threadIdx.x;
        atomicAdd(&statsOut[128 + ch], red[ch] + red[128 + ch] + red[256 + ch] + red[384 + ch]);
    }
}

// ---------------- pooling (sorted batch ranges) + readout MLP ----------------

__global__ __launch_bounds__(128) void k_pool(const unsigned short* __restrict__ agg,
                                              const float* __restrict__ stats4,
                                              const float* __restrict__ gamma4,
                                              const float* __restrict__ beta4,
                                              const int* __restrict__ gstart,
                                              const float* __restrict__ W1, const float* __restrict__ b1,
                                              const float* __restrict__ W2, const float* __restrict__ b2,
                                              const float* __restrict__ W3, const float* __restrict__ b3,
                                              float* __restrict__ out) {
    __shared__ float mol[128];
    __shared__ float h1s[128];
    const int g = blockIdx.x;
    const int c = threadIdx.x;
    const float m = stats4[c] * INV_N;
    const float var = stats4[128 + c] * INV_N - m * m;
    const float sc = gamma4[c] * rsqrtf(var + BN_EPS);
    const float sh = fmaf(-m, sc, beta4[c]);
    const int v0 = gstart[g], v1 = gstart[g + 1];
    float acc = 0.f;
    for (int v = v0; v < v1; ++v)
        acc += fmaf(bf2f(agg[(size_t)v * 128 + c]), sc, sh);  // last layer: BN, no relu
    mol[c] = acc;
    __syncthreads();
    float a1 = b1[c];
    #pragma unroll 8
    for (int k = 0; k < 128; ++k) a1 = fmaf(mol[k], W1[k * 128 + c], a1);
    h1s[c] = fmaxf(a1, 0.f);
    __syncthreads();
    if (c < 64) {
        float a2 = b2[c];
        #pragma unroll 8
        for (int k = 0; k < 128; ++k) a2 = fmaf(h1s[k], W2[k * 64 + c], a2);
        float p = fmaxf(a2, 0.f) * W3[c];
        #pragma unroll
        for (int o = 32; o > 0; o >>= 1) p += __shfl_down(p, o);
        if (c == 0) out[g] = p + b3[0];
    }
}

// ---------------- launch ----------------

extern "C" void kernel_launch(void* const* d_in, const int* in_sizes, int n_in,
                              void* d_out, int out_size, void* d_ws, size_t ws_size,
                              hipStream_t stream) {
    (void)in_sizes; (void)n_in; (void)out_size; (void)ws_size;
    const float* x     = (const float*)d_in[0];
    const int*   ei    = (const int*)d_in[1];
    const int*   batch = (const int*)d_in[2];
    const float* Wx    = (const float*)d_in[3];
    const float* bx    = (const float*)d_in[4];
    const float* Wg    = (const float*)d_in[5];
    const float* bg    = (const float*)d_in[6];
    const float* gamma = (const float*)d_in[7];
    const float* beta  = (const float*)d_in[8];
    const float* W1    = (const float*)d_in[9];
    const float* b1    = (const float*)d_in[10];
    const float* W2    = (const float*)d_in[11];
    const float* b2    = (const float*)d_in[12];
    const float* W3    = (const float*)d_in[13];
    const float* b3    = (const float*)d_in[14];
    float* out = (float*)d_out;

    char* ws = (char*)d_ws;
    size_t off = 0;
    auto alloc = [&](size_t bytes) -> char* {
        char* p = ws + off;
        off += (bytes + 255) & ~(size_t)255;
        return p;
    };
    unsigned short* aggA   = (unsigned short*)alloc((size_t)NNODES * 128 * 2);
    unsigned short* aggB   = (unsigned short*)alloc((size_t)NNODES * 128 * 2);
    unsigned short* xw     = (unsigned short*)alloc((size_t)NNODES * 128 * 2);
    float*          dinv   = (float*)alloc((size_t)NNODES * 4);
    int*            cnt    = (int*)alloc((size_t)NNODES * 4);
    int*            cursor = (int*)alloc((size_t)NNODES * 4);
    int*            roff   = (int*)alloc((size_t)(NNODES + 1) * 4);
    int2*           cedge  = (int2*)alloc((size_t)(NE2 + 4) * 8);
    char*           wt     = alloc((size_t)NLAYERS * 32768);
    char*           wxt    = alloc((size_t)16384);
    float*          stats  = (float*)alloc((size_t)NLAYERS * 256 * 4);
    int*            gstart = (int*)alloc((size_t)(NGRAPHS + 1) * 4);
    int*            bsum   = (int*)alloc((size_t)1024 * 4);

    const int NB = (NNODES + 255) / 256;   // 782
    const int EB = (NEDGES + 255) / 256;   // 1563
    const int GB = (NNODES + 127) / 128;   // 1563 gemm tiles
    const int WB = (NLAYERS * 16384 + 8192 + 255) / 256;

    k_init<<<NB, 256, 0, stream>>>(cnt, cursor, stats, cedge + NE2);
    k_count<<<EB, 256, 0, stream>>>(ei, cnt);
    k_scan1<<<NB, 256, 0, stream>>>(cnt, roff, bsum, batch, gstart);
    k_scan2<<<1, 1024, 0, stream>>>(bsum, NB);
    k_scan3<<<NB, 256, 0, stream>>>(roff, bsum, cnt, dinv, cedge);
    k_fill<<<EB, 256, 0, stream>>>(ei, dinv, roff, cursor, cedge);
    k_wtrans<<<WB, 256, 0, stream>>>(Wg, Wx, bx, wt, wxt);
    k_inproj<<<GB, 256, 0, stream>>>(x, wxt, aggA);

    unsigned short* cur = aggA;
    unsigned short* nxt = aggB;
    for (int l = 0; l < NLAYERS; ++l) {
        const float* sp = (l > 0) ? (stats + (l - 1) * 256) : (const float*)nullptr;
        const float* gp = (l > 0) ? (gamma + (l - 1) * 128) : (const float*)nullptr;
        const float* bp = (l > 0) ? (beta + (l - 1) * 128) : (const float*)nullptr;
        k_gemm<<<GB, 256, 0, stream>>>(cur, wt + (size_t)l * 32768, xw, sp, gp, bp, l > 0);
        k_agg<<<2560, 256, 0, stream>>>(cur, xw, roff, cedge, bg + l * 128,
                                        sp, gp, bp, l > 0, nxt, stats + l * 256);
        unsigned short* t = cur; cur = nxt; nxt = t;
    }

    k_pool<<<NGRAPHS, 128, 0, stream>>>(cur, stats + 4 * 256, gamma + 4 * 128, beta + 4 * 128,
                                        gstart, W1, b1, W2, b2, W3, b3, out);
}

// Round 9
// 956.990 us; speedup vs baseline: 1.0023x; 1.0023x over previous
//
#include <hip/hip_runtime.h>
#include <stdint.h>

#define NNODES  200000
#define NEDGES  400000
#define NE2     (NEDGES + NNODES)   // edges + self-loops in CSR
#define NGRAPHS 4000
#define NLAYERS 5
#define BN_EPS  1e-5f
#define INV_N   (1.0f / (float)NNODES)

typedef __attribute__((ext_vector_type(8))) short short8;
typedef __attribute__((ext_vector_type(4))) float f32x4;

__device__ __forceinline__ unsigned int f2bf(float f) {
    unsigned int u = __float_as_uint(f);
    return (u + 0x7fffu + ((u >> 16) & 1u)) >> 16;
}
__device__ __forceinline__ float bf2f(unsigned int b) {
    return __uint_as_float(b << 16);
}

__device__ __forceinline__ void acc8(float (&a)[8], float wgt, const uint4& g) {
    a[0] = fmaf(wgt, bf2f(g.x & 0xffffu), a[0]);
    a[1] = fmaf(wgt, bf2f(g.x >> 16),     a[1]);
    a[2] = fmaf(wgt, bf2f(g.y & 0xffffu), a[2]);
    a[3] = fmaf(wgt, bf2f(g.y >> 16),     a[3]);
    a[4] = fmaf(wgt, bf2f(g.z & 0xffffu), a[4]);
    a[5] = fmaf(wgt, bf2f(g.z >> 16),     a[5]);
    a[6] = fmaf(wgt, bf2f(g.w & 0xffffu), a[6]);
    a[7] = fmaf(wgt, bf2f(g.w >> 16),     a[7]);
}

// ---------------- graph prep ----------------

__global__ void k_init(int* __restrict__ cnt, int* __restrict__ cursor,
                       float* __restrict__ stats, int2* __restrict__ cedge_tail) {
    int i = blockIdx.x * 256 + threadIdx.x;
    if (i < NNODES) { cnt[i] = 0; cursor[i] = 0; }
    if (i < NLAYERS * 256) stats[i] = 0.f;
    if (i < 4) { int2 z; z.x = 0; z.y = 0; cedge_tail[i] = z; }  // zero CSR pad
}

__global__ void k_count(const int* __restrict__ ei, int* __restrict__ cnt) {
    int e = blockIdx.x * 256 + threadIdx.x;
    if (e < NEDGES) atomicAdd(&cnt[ei[NEDGES + e]], 1);
}

// block-scan of (cnt[v]+1) [self-loop included]; also graph ranges from sorted batch
__global__ __launch_bounds__(256) void k_scan1(const int* __restrict__ cnt,
                                               int* __restrict__ roff, int* __restrict__ bsum,
                                               const int* __restrict__ batch,
                                               int* __restrict__ gstart) {
    __shared__ int s[256];
    int t = threadIdx.x;
    int v = blockIdx.x * 256 + t;
    int val = (v < NNODES) ? cnt[v] + 1 : 0;
    s[t] = val; __syncthreads();
    int sum = val;
    for (int o = 1; o < 256; o <<= 1) {
        int tmp = (t >= o) ? s[t - o] : 0;
        __syncthreads();
        sum += tmp; s[t] = sum;
        __syncthreads();
    }
    if (v < NNODES) roff[v] = sum - val;       // exclusive within block
    if (t == 255) bsum[blockIdx.x] = s[255];

    if (v < NNODES) {   // graph ranges (merged k_ranges)
        int b = batch[v];
        if (v == 0) {
            for (int g = 0; g <= b; ++g) gstart[g] = 0;
        } else {
            int pb = batch[v - 1];
            for (int g = pb + 1; g <= b; ++g) gstart[g] = v;
        }
        if (v == NNODES - 1) {
            for (int g = b + 1; g <= NGRAPHS; ++g) gstart[g] = NNODES;
        }
    }
}

__global__ __launch_bounds__(1024) void k_scan2(int* __restrict__ bsum, int nb) {
    __shared__ int s[1024];
    int t = threadIdx.x;
    int val = (t < nb) ? bsum[t] : 0;
    s[t] = val; __syncthreads();
    int sum = val;
    for (int o = 1; o < 1024; o <<= 1) {
        int tmp = (t >= o) ? s[t - o] : 0;
        __syncthreads();
        sum += tmp; s[t] = sum;
        __syncthreads();
    }
    if (t < nb) bsum[t] = sum - val;           // exclusive block offsets
}

// finalize roff; compute dinv; write the self-loop edge at slot roff[v]
__global__ void k_scan3(int* __restrict__ roff, const int* __restrict__ bsum,
                        const int* __restrict__ cnt, float* __restrict__ dinv,
                        int2* __restrict__ cedge) {
    int v = blockIdx.x * 256 + threadIdx.x;
    if (v < NNODES) {
        int r = roff[v] + bsum[blockIdx.x];
        roff[v] = r;
        float dv = rsqrtf((float)cnt[v] + 1.0f);
        dinv[v] = dv;
        int2 se; se.x = v; se.y = __float_as_int(dv * dv);
        cedge[r] = se;
    }
    if (v == 0) roff[NNODES] = NE2;
}

// real edges go to slots roff[d]+1+pos (slot 0 is the self-loop)
__global__ void k_fill(const int* __restrict__ ei, const float* __restrict__ dinv,
                       const int* __restrict__ roff, int* __restrict__ cursor,
                       int2* __restrict__ cedge) {
    int e = blockIdx.x * 256 + threadIdx.x;
    if (e >= NEDGES) return;
    int s = ei[e], d = ei[NEDGES + e];
    int pos = atomicAdd(&cursor[d], 1);
    int idx = roff[d] + 1 + pos;
    int2 ed; ed.x = s; ed.y = __float_as_int(dinv[s] * dinv[d]);
    cedge[idx] = ed;
}

// transpose + bf16-convert + swizzle layer weights WT[n][k]=W[k][n] (256B rows),
// and Wx -> WxT[n][k0..63] zero-padded (128B rows), with bias folded at k=40.
__global__ void k_wtrans(const float* __restrict__ Wg, const float* __restrict__ Wx,
                         const float* __restrict__ bx,
                         char* __restrict__ wt, char* __restrict__ wxt) {
    int idx = blockIdx.x * 256 + threadIdx.x;
    if (idx < NLAYERS * 16384) {
        int l = idx >> 14;
        int rem = idx & 16383;
        int n = rem >> 7;
        int k = rem & 127;
        float v = Wg[l * 16384 + k * 128 + n];
        char* img = wt + l * 32768;
        *(unsigned short*)(img + (n << 8) + ((k << 1) ^ ((n & 7) << 4))) = (unsigned short)f2bf(v);
    } else if (idx < NLAYERS * 16384 + 8192) {
        int j = idx - NLAYERS * 16384;
        int n = j >> 6;
        int k = j & 63;
        float v = (k < 40) ? Wx[k * 128 + n] : (k == 40 ? bx[n] : 0.f);
        *(unsigned short*)(wxt + (n << 7) + ((k << 1) ^ ((n & 7) << 4))) = (unsigned short)f2bf(v);
    }
}

// ---------------- input projection (MFMA): h0 = bf16(x @ Wx + bx) ----------------

__global__ __launch_bounds__(256) void k_inproj(const float* __restrict__ x,
                                                const char* __restrict__ wxt,
                                                unsigned short* __restrict__ out) {
    __shared__ char As[16384];   // 128 rows * 128 B
    const int tid = threadIdx.x;
    const int m0 = blockIdx.x << 7;

    { // stage A: 16 threads per row cover k 0..63 (4 each); k=40 -> 1.0
        const int kq = (tid & 15) << 2;   // 0,4,...,60
        const int r0 = tid >> 4;          // 0..15
        #pragma unroll
        for (int it = 0; it < 8; ++it) {
            const int r = r0 + (it << 4);
            const int grow = m0 + r;
            float x0 = 0.f, x1 = 0.f, x2 = 0.f, x3 = 0.f;
            if (grow < NNODES) {
                if (kq < 40) {
                    const float4 v = *(const float4*)(x + (size_t)grow * 40 + kq);
                    x0 = v.x; x1 = v.y; x2 = v.z; x3 = v.w;
                } else if (kq == 40) {
                    x0 = 1.0f;   // homogeneous coordinate -> bias via MFMA
                }
            }
            uint2 p;
            p.x = f2bf(x0) | (f2bf(x1) << 16);
            p.y = f2bf(x2) | (f2bf(x3) << 16);
            *(uint2*)(As + (r << 7) + ((kq << 1) ^ ((r & 7) << 4))) = p;
        }
    }
    __syncthreads();

    const int lane = tid & 63;
    const int wid = tid >> 6;
    const int l15 = lane & 15;
    const int lq = lane >> 4;

    const f32x4 zero = {0.f, 0.f, 0.f, 0.f};
    f32x4 acc[2][8];
    #pragma unroll
    for (int i = 0; i < 2; ++i)
        #pragma unroll
        for (int j = 0; j < 8; ++j) acc[i][j] = zero;

    #pragma unroll
    for (int kk = 0; kk < 2; ++kk) {
        const int kb = (kk << 6) + (lq << 4);
        short8 afr[2];
        #pragma unroll
        for (int rt = 0; rt < 2; ++rt) {
            const int r = (wid << 5) + (rt << 4) + l15;
            afr[rt] = *(const short8*)(As + (r << 7) + (kb ^ ((r & 7) << 4)));
        }
        #pragma unroll
        for (int ct = 0; ct < 8; ++ct) {
            const int n = (ct << 4) + l15;
            const short8 bfr = *(const short8*)(wxt + (n << 7) + (kb ^ ((n & 7) << 4)));
            acc[0][ct] = __builtin_amdgcn_mfma_f32_16x16x32_bf16(bfr, afr[0], acc[0][ct], 0, 0, 0);
            acc[1][ct] = __builtin_amdgcn_mfma_f32_16x16x32_bf16(bfr, afr[1], acc[1][ct], 0, 0, 0);
        }
    }

    #pragma unroll
    for (int rt = 0; rt < 2; ++rt) {
        const int grow = m0 + (wid << 5) + (rt << 4) + l15;   // node
        if (grow < NNODES) {
            #pragma unroll
            for (int ct = 0; ct < 8; ++ct) {
                uint2 pk;
                pk.x = f2bf(acc[rt][ct][0]) | (f2bf(acc[rt][ct][1]) << 16);
                pk.y = f2bf(acc[rt][ct][2]) | (f2bf(acc[rt][ct][3]) << 16);
                *(uint2*)(out + (size_t)grow * 128 + (ct << 4) + (lq << 2)) = pk;
            }
        }
    }
}

// ---------------- per-layer GEMM: xw(bf16) = BNrelu(in_bf16) @ Wg[l] ----------------
// B staged to LDS via global_load_lds (issued first, lands during A-stage);
// BN coefficients computed inline from raw stats (no bnfin kernel).

__global__ __launch_bounds__(256) void k_gemm(const unsigned short* __restrict__ in,
                                              const char* __restrict__ wt,
                                              unsigned short* __restrict__ out,
                                              const float* __restrict__ statsPrev,
                                              const float* __restrict__ gamma,
                                              const float* __restrict__ beta,
                                              int apply_bn) {
    __shared__ char As[32768];   // A tile, swizzled 256B rows
    __shared__ char Bs[32768];   // W^T image copy

    const int tid = threadIdx.x;
    const int lane = tid & 63;
    const int wid = tid >> 6;
    const int m0 = blockIdx.x << 7;

    { // issue B staging first: 32 chunks of 1KB, wave-linear global_load_lds
        #pragma unroll
        for (int i = 0; i < 8; ++i) {
            const int chunk = ((i << 2) + wid) << 10;   // (i*4 + wave) * 1024
            __builtin_amdgcn_global_load_lds(
                (const __attribute__((address_space(1))) unsigned int*)(wt + chunk + (lane << 4)),
                (__attribute__((address_space(3))) unsigned int*)(Bs + chunk),
                16, 0, 0);
        }
    }
    { // stage A: load bf16, BN+relu in fp32, back to bf16, swizzled ds_write
        const int c0 = (tid & 31) << 2;
        float scv[4] = {1.f, 1.f, 1.f, 1.f};
        float shv[4] = {0.f, 0.f, 0.f, 0.f};
        if (apply_bn) {
            #pragma unroll
            for (int j = 0; j < 4; ++j) {
                const float m = statsPrev[c0 + j] * INV_N;
                const float var = statsPrev[128 + c0 + j] * INV_N - m * m;
                const float s = gamma[c0 + j] * rsqrtf(var + BN_EPS);
                scv[j] = s;
                shv[j] = fmaf(-m, s, beta[c0 + j]);
            }
        }
        const int r0 = tid >> 5;
        #pragma unroll
        for (int it = 0; it < 16; ++it) {
            const int r = r0 + (it << 3);
            const int grow = m0 + r;
            uint2 p = {0u, 0u};
            if (grow < NNODES) {
                const uint2 raw = *(const uint2*)(in + (size_t)grow * 128 + c0);
                if (apply_bn) {
                    float x0 = fmaxf(fmaf(bf2f(raw.x & 0xffffu), scv[0], shv[0]), 0.f);
                    float x1 = fmaxf(fmaf(bf2f(raw.x >> 16),     scv[1], shv[1]), 0.f);
                    float x2 = fmaxf(fmaf(bf2f(raw.y & 0xffffu), scv[2], shv[2]), 0.f);
                    float x3 = fmaxf(fmaf(bf2f(raw.y >> 16),     scv[3], shv[3]), 0.f);
                    p.x = f2bf(x0) | (f2bf(x1) << 16);
                    p.y = f2bf(x2) | (f2bf(x3) << 16);
                } else {
                    p = raw;   // already bf16
                }
            }
            *(uint2*)(As + (r << 8) + ((c0 << 1) ^ ((r & 7) << 4))) = p;
        }
    }
    __syncthreads();   // drains vmcnt -> Bs ready too

    const int l15 = lane & 15;
    const int lq = lane >> 4;

    const f32x4 zero = {0.f, 0.f, 0.f, 0.f};
    f32x4 acc[2][8];
    #pragma unroll
    for (int i = 0; i < 2; ++i)
        #pragma unroll
        for (int j = 0; j < 8; ++j) acc[i][j] = zero;

    #pragma unroll
    for (int kk = 0; kk < 4; ++kk) {
        const int kb = (kk << 6) + (lq << 4);
        short8 afr[2];
        #pragma unroll
        for (int rt = 0; rt < 2; ++rt) {
            const int r = (wid << 5) + (rt << 4) + l15;
            afr[rt] = *(const short8*)(As + (r << 8) + (kb ^ ((r & 7) << 4)));
        }
        #pragma unroll
        for (int ct = 0; ct < 8; ++ct) {
            const int n = (ct << 4) + l15;
            const short8 bfr = *(const short8*)(Bs + (n << 8) + (kb ^ ((n & 7) << 4)));
            // swapped operands: D[channel][node]
            acc[0][ct] = __builtin_amdgcn_mfma_f32_16x16x32_bf16(bfr, afr[0], acc[0][ct], 0, 0, 0);
            acc[1][ct] = __builtin_amdgcn_mfma_f32_16x16x32_bf16(bfr, afr[1], acc[1][ct], 0, 0, 0);
        }
    }

    #pragma unroll
    for (int rt = 0; rt < 2; ++rt) {
        const int grow = m0 + (wid << 5) + (rt << 4) + l15;   // node
        if (grow < NNODES) {
            #pragma unroll
            for (int ct = 0; ct < 8; ++ct) {
                uint2 pk;
                pk.x = f2bf(acc[rt][ct][0]) | (f2bf(acc[rt][ct][1]) << 16);
                pk.y = f2bf(acc[rt][ct][2]) | (f2bf(acc[rt][ct][3]) << 16);
                *(uint2*)(out + (size_t)grow * 128 + (ct << 4) + (lq << 2)) = pk;
            }
        }
    }
}

// ------- aggregation: agg_l = bg + BNrelu(prev) + sum over CSR(self included) -------
// R6-proven structure: 4 nodes/wave (16 lanes x 8ch); batch-4 edges with FOUR
// ALIGNED int2 metadata loads (R8's uint4 at odd e was misaligned -> regression);
// no cross-sweep prefetch (keeps VGPR ~52). Self-loop is CSR entry 0.

__global__ __launch_bounds__(256) void k_agg(const unsigned short* __restrict__ prev,
                                             const unsigned short* __restrict__ xw,
                                             const int* __restrict__ roff,
                                             const int2* __restrict__ cedge,
                                             const float* __restrict__ bg,
                                             const float* __restrict__ statsPrev,
                                             const float* __restrict__ gamma,
                                             const float* __restrict__ beta,
                                             int apply_bn,
                                             unsigned short* __restrict__ outb,
                                             float* __restrict__ statsOut) {
    const int lane = threadIdx.x & 63;
    const int wv   = threadIdx.x >> 6;       // wave 0..3
    const int g16  = lane >> 4;              // node slot within wave 0..3
    const int l16  = lane & 15;
    const int c8   = l16 << 3;               // channel base (8 channels per lane)

    float sc[8], sh[8], bgv[8];
    #pragma unroll
    for (int j = 0; j < 8; ++j) {
        if (apply_bn) {
            const float m = statsPrev[c8 + j] * INV_N;
            const float var = statsPrev[128 + c8 + j] * INV_N - m * m;
            const float s = gamma[c8 + j] * rsqrtf(var + BN_EPS);
            sc[j] = s;
            sh[j] = fmaf(-m, s, beta[c8 + j]);
        } else { sc[j] = 1.f; sh[j] = 0.f; }
        bgv[j] = bg[c8 + j];
    }
    float s_[8], q_[8];
    #pragma unroll
    for (int j = 0; j < 8; ++j) { s_[j] = 0.f; q_[j] = 0.f; }

    const int stride = gridDim.x * 16;
    for (int v = blockIdx.x * 16 + wv * 4 + g16; v < NNODES; v += stride) {
        const int rof0 = roff[v];
        const int rof1 = roff[v + 1];
        const uint4 resu = *(const uint4*)(prev + (size_t)v * 128 + c8);
        float a[8];
        {
            float r[8];
            r[0] = bf2f(resu.x & 0xffffu); r[1] = bf2f(resu.x >> 16);
            r[2] = bf2f(resu.y & 0xffffu); r[3] = bf2f(resu.y >> 16);
            r[4] = bf2f(resu.z & 0xffffu); r[5] = bf2f(resu.z >> 16);
            r[6] = bf2f(resu.w & 0xffffu); r[7] = bf2f(resu.w >> 16);
            if (apply_bn) {
                #pragma unroll
                for (int j = 0; j < 8; ++j)
                    a[j] = bgv[j] + fmaxf(fmaf(r[j], sc[j], sh[j]), 0.f);
            } else {
                #pragma unroll
                for (int j = 0; j < 8; ++j) a[j] = bgv[j] + r[j];
            }
        }
        int e = rof0;
        while (e < rof1) {   // >=1 iteration: self-loop is entry 0
            const int rem = rof1 - e;
            const int2 d0 = cedge[e];
            const int2 d1 = cedge[rem > 1 ? e + 1 : e];
            const int2 d2 = cedge[rem > 2 ? e + 2 : e];
            const int2 d3 = cedge[rem > 3 ? e + 3 : e];
            const float w0 = __int_as_float(d0.y);
            const float w1 = rem > 1 ? __int_as_float(d1.y) : 0.f;
            const float w2 = rem > 2 ? __int_as_float(d2.y) : 0.f;
            const float w3 = rem > 3 ? __int_as_float(d3.y) : 0.f;
            const uint4 g0 = *(const uint4*)(xw + (size_t)d0.x * 128 + c8);
            const uint4 g1 = *(const uint4*)(xw + (size_t)d1.x * 128 + c8);
            const uint4 g2 = *(const uint4*)(xw + (size_t)d2.x * 128 + c8);
            const uint4 g3 = *(const uint4*)(xw + (size_t)d3.x * 128 + c8);
            acc8(a, w0, g0);
            acc8(a, w1, g1);
            acc8(a, w2, g2);
            acc8(a, w3, g3);
            e += 4;
        }
        uint4 o;
        o.x = f2bf(a[0]) | (f2bf(a[1]) << 16);
        o.y = f2bf(a[2]) | (f2bf(a[3]) << 16);
        o.z = f2bf(a[4]) | (f2bf(a[5]) << 16);
        o.w = f2bf(a[6]) | (f2bf(a[7]) << 16);
        *(uint4*)(outb + (size_t)v * 128 + c8) = o;
        #pragma unroll
        for (int j = 0; j < 8; ++j) {
            s_[j] += a[j];
            q_[j] = fmaf(a[j], a[j], q_[j]);
        }
    }

    // combine the 4 node-slots (channels depend on l16 only)
    #pragma unroll
    for (int j = 0; j < 8; ++j) {
        s_[j] += __shfl_xor(s_[j], 16); s_[j] += __shfl_xor(s_[j], 32);
        q_[j] += __shfl_xor(q_[j], 16); q_[j] += __shfl_xor(q_[j], 32);
    }
    __shared__ float red[512];
    if (g16 == 0) {
        #pragma unroll
        for (int j = 0; j < 8; ++j) red[wv * 128 + c8 + j] = s_[j];
    }
    __syncthreads();
    if (threadIdx.x < 128) {
        const int ch = threadIdx.x;
        atomicAdd(&statsOut[ch], red[ch] + red[128 + ch] + red[256 + ch] + red[384 + ch]);
    }
    __syncthreads();
    if (g16 == 0) {
        #pragma unroll
        for (int j = 0; j < 8; ++j) red[wv * 128 + c8 + j] = q_[j];
    }
    __syncthreads();
    if (threadIdx.x < 128) {
        const int ch = threadIdx.x;
        atomicAdd(&statsOut[128 + ch], red[ch] + red[128 + ch] + red[256 + ch] + red[384 + ch]);
    }
}

// ---------------- pooling (sorted batch ranges) + readout MLP ----------------

__global__ __launch_bounds__(128) void k_pool(const unsigned short* __restrict__ agg,
                                              const float* __restrict__ stats4,
                                              const float* __restrict__ gamma4,
                                              const float* __restrict__ beta4,
                                              const int* __restrict__ gstart,
                                              const float* __restrict__ W1, const float* __restrict__ b1,
                                              const float* __restrict__ W2, const float* __restrict__ b2,
                                              const float* __restrict__ W3, const float* __restrict__ b3,
                                              float* __restrict__ out) {
    __shared__ float mol[128];
    __shared__ float h1s[128];
    const int g = blockIdx.x;
    const int c = threadIdx.x;
    const float m = stats4[c] * INV_N;
    const float var = stats4[128 + c] * INV_N - m * m;
    const float sc = gamma4[c] * rsqrtf(var + BN_EPS);
    const float sh = fmaf(-m, sc, beta4[c]);
    const int v0 = gstart[g], v1 = gstart[g + 1];
    float acc = 0.f;
    for (int v = v0; v < v1; ++v)
        acc += fmaf(bf2f(agg[(size_t)v * 128 + c]), sc, sh);  // last layer: BN, no relu
    mol[c] = acc;
    __syncthreads();
    float a1 = b1[c];
    #pragma unroll 8
    for (int k = 0; k < 128; ++k) a1 = fmaf(mol[k], W1[k * 128 + c], a1);
    h1s[c] = fmaxf(a1, 0.f);
    __syncthreads();
    if (c < 64) {
        float a2 = b2[c];
        #pragma unroll 8
        for (int k = 0; k < 128; ++k) a2 = fmaf(h1s[k], W2[k * 64 + c], a2);
        float p = fmaxf(a2, 0.f) * W3[c];
        #pragma unroll
        for (int o = 32; o > 0; o >>= 1) p += __shfl_down(p, o);
        if (c == 0) out[g] = p + b3[0];
    }
}

// ---------------- launch ----------------

extern "C" void kernel_launch(void* const* d_in, const int* in_sizes, int n_in,
                              void* d_out, int out_size, void* d_ws, size_t ws_size,
                              hipStream_t stream) {
    (void)in_sizes; (void)n_in; (void)out_size; (void)ws_size;
    const float* x     = (const float*)d_in[0];
    const int*   ei    = (const int*)d_in[1];
    const int*   batch = (const int*)d_in[2];
    const float* Wx    = (const float*)d_in[3];
    const float* bx    = (const float*)d_in[4];
    const float* Wg    = (const float*)d_in[5];
    const float* bg    = (const float*)d_in[6];
    const float* gamma = (const float*)d_in[7];
    const float* beta  = (const float*)d_in[8];
    const float* W1    = (const float*)d_in[9];
    const float* b1    = (const float*)d_in[10];
    const float* W2    = (const float*)d_in[11];
    const float* b2    = (const float*)d_in[12];
    const float* W3    = (const float*)d_in[13];
    const float* b3    = (const float*)d_in[14];
    float* out = (float*)d_out;

    char* ws = (char*)d_ws;
    size_t off = 0;
    auto alloc = [&](size_t bytes) -> char* {
        char* p = ws + off;
        off += (bytes + 255) & ~(size_t)255;
        return p;
    };
    unsigned short* aggA   = (unsigned short*)alloc((size_t)NNODES * 128 * 2);
    unsigned short* aggB   = (unsigned short*)alloc((size_t)NNODES * 128 * 2);
    unsigned short* xw     = (unsigned short*)alloc((size_t)NNODES * 128 * 2);
    float*          dinv   = (float*)alloc((size_t)NNODES * 4);
    int*            cnt    = (int*)alloc((size_t)NNODES * 4);
    int*            cursor = (int*)alloc((size_t)NNODES * 4);
    int*            roff   = (int*)alloc((size_t)(NNODES + 1) * 4);
    int2*           cedge  = (int2*)alloc((size_t)(NE2 + 4) * 8);
    char*           wt     = alloc((size_t)NLAYERS * 32768);
    char*           wxt    = alloc((size_t)16384);
    float*          stats  = (float*)alloc((size_t)NLAYERS * 256 * 4);
    int*            gstart = (int*)alloc((size_t)(NGRAPHS + 1) * 4);
    int*            bsum   = (int*)alloc((size_t)1024 * 4);

    const int NB = (NNODES + 255) / 256;   // 782
    const int EB = (NEDGES + 255) / 256;   // 1563
    const int GB = (NNODES + 127) / 128;   // 1563 gemm tiles
    const int WB = (NLAYERS * 16384 + 8192 + 255) / 256;

    k_init<<<NB, 256, 0, stream>>>(cnt, cursor, stats, cedge + NE2);
    k_count<<<EB, 256, 0, stream>>>(ei, cnt);
    k_scan1<<<NB, 256, 0, stream>>>(cnt, roff, bsum, batch, gstart);
    k_scan2<<<1, 1024, 0, stream>>>(bsum, NB);
    k_scan3<<<NB, 256, 0, stream>>>(roff, bsum, cnt, dinv, cedge);
    k_fill<<<EB, 256, 0, stream>>>(ei, dinv, roff, cursor, cedge);
    k_wtrans<<<WB, 256, 0, stream>>>(Wg, Wx, bx, wt, wxt);
    k_inproj<<<GB, 256, 0, stream>>>(x, wxt, aggA);

    unsigned short* cur = aggA;
    unsigned short* nxt = aggB;
    for (int l = 0; l < NLAYERS; ++l) {
        const float* sp = (l > 0) ? (stats + (l - 1) * 256) : (const float*)nullptr;
        const float* gp = (l > 0) ? (gamma + (l - 1) * 128) : (const float*)nullptr;
        const float* bp = (l > 0) ? (beta + (l - 1) * 128) : (const float*)nullptr;
        k_gemm<<<GB, 256, 0, stream>>>(cur, wt + (size_t)l * 32768, xw, sp, gp, bp, l > 0);
        k_agg<<<2560, 256, 0, stream>>>(cur, xw, roff, cedge, bg + l * 128,
                                        sp, gp, bp, l > 0, nxt, stats + l * 256);
        unsigned short* t = cur; cur = nxt; nxt = t;
    }

    k_pool<<<NGRAPHS, 128, 0, stream>>>(cur, stats + 4 * 256, gamma + 4 * 128, beta + 4 * 128,
                                        gstart, W1, b1, W2, b2, W3, b3, out);
}

// Round 10
// 866.785 us; speedup vs baseline: 1.1066x; 1.1041x over previous
//
#include <hip/hip_runtime.h>
#include <stdint.h>

#define NNODES  200000
#define NEDGES  400000
#define NGRAPHS 4000
#define NLAYERS 5
#define BN_EPS  1e-5f
#define INV_N   (1.0f / (float)NNODES)
#define NTILES  ((NNODES + 127) / 128)   // 1563

typedef __attribute__((ext_vector_type(8))) short short8;
typedef __attribute__((ext_vector_type(4))) float f32x4;

__device__ __forceinline__ unsigned int f2bf(float f) {
    unsigned int u = __float_as_uint(f);
    return (u + 0x7fffu + ((u >> 16) & 1u)) >> 16;
}
__device__ __forceinline__ float bf2f(unsigned int b) {
    return __uint_as_float(b << 16);
}

__device__ __forceinline__ void acc8(float (&a)[8], float wgt, const uint4& g) {
    a[0] = fmaf(wgt, bf2f(g.x & 0xffffu), a[0]);
    a[1] = fmaf(wgt, bf2f(g.x >> 16),     a[1]);
    a[2] = fmaf(wgt, bf2f(g.y & 0xffffu), a[2]);
    a[3] = fmaf(wgt, bf2f(g.y >> 16),     a[3]);
    a[4] = fmaf(wgt, bf2f(g.z & 0xffffu), a[4]);
    a[5] = fmaf(wgt, bf2f(g.z >> 16),     a[5]);
    a[6] = fmaf(wgt, bf2f(g.w & 0xffffu), a[6]);
    a[7] = fmaf(wgt, bf2f(g.w >> 16),     a[7]);
}

// ---------------- graph prep ----------------

__global__ void k_init(int* __restrict__ cnt, int* __restrict__ cursor,
                       float* __restrict__ stats) {
    int i = blockIdx.x * 256 + threadIdx.x;
    if (i < NNODES) { cnt[i] = 0; cursor[i] = 0; }
    if (i < NLAYERS * 256) stats[i] = 0.f;
}

__global__ void k_count(const int* __restrict__ ei, int* __restrict__ cnt) {
    int e = blockIdx.x * 256 + threadIdx.x;
    if (e < NEDGES) atomicAdd(&cnt[ei[NEDGES + e]], 1);
}

// block-scan of cnt (real edges only); also graph ranges from sorted batch
__global__ __launch_bounds__(256) void k_scan1(const int* __restrict__ cnt,
                                               int* __restrict__ roff, int* __restrict__ bsum,
                                               const int* __restrict__ batch,
                                               int* __restrict__ gstart) {
    __shared__ int s[256];
    int t = threadIdx.x;
    int v = blockIdx.x * 256 + t;
    int val = (v < NNODES) ? cnt[v] : 0;
    s[t] = val; __syncthreads();
    int sum = val;
    for (int o = 1; o < 256; o <<= 1) {
        int tmp = (t >= o) ? s[t - o] : 0;
        __syncthreads();
        sum += tmp; s[t] = sum;
        __syncthreads();
    }
    if (v < NNODES) roff[v] = sum - val;       // exclusive within block
    if (t == 255) bsum[blockIdx.x] = s[255];

    if (v < NNODES) {   // graph ranges (merged k_ranges)
        int b = batch[v];
        if (v == 0) {
            for (int g = 0; g <= b; ++g) gstart[g] = 0;
        } else {
            int pb = batch[v - 1];
            for (int g = pb + 1; g <= b; ++g) gstart[g] = v;
        }
        if (v == NNODES - 1) {
            for (int g = b + 1; g <= NGRAPHS; ++g) gstart[g] = NNODES;
        }
    }
}

__global__ __launch_bounds__(1024) void k_scan2(int* __restrict__ bsum, int nb) {
    __shared__ int s[1024];
    int t = threadIdx.x;
    int val = (t < nb) ? bsum[t] : 0;
    s[t] = val; __syncthreads();
    int sum = val;
    for (int o = 1; o < 1024; o <<= 1) {
        int tmp = (t >= o) ? s[t - o] : 0;
        __syncthreads();
        sum += tmp; s[t] = sum;
        __syncthreads();
    }
    if (t < nb) bsum[t] = sum - val;           // exclusive block offsets
}

// finalize roff; compute dinv
__global__ void k_scan3(int* __restrict__ roff, const int* __restrict__ bsum,
                        const int* __restrict__ cnt, float* __restrict__ dinv) {
    int v = blockIdx.x * 256 + threadIdx.x;
    if (v < NNODES) {
        roff[v] += bsum[blockIdx.x];
        dinv[v] = rsqrtf((float)cnt[v] + 1.0f);
    }
    if (v == 0) roff[NNODES] = NEDGES;
}

__global__ void k_fill(const int* __restrict__ ei, const float* __restrict__ dinv,
                       const int* __restrict__ roff, int* __restrict__ cursor,
                       int2* __restrict__ cedge) {
    int e = blockIdx.x * 256 + threadIdx.x;
    if (e >= NEDGES) return;
    int s = ei[e], d = ei[NEDGES + e];
    int pos = atomicAdd(&cursor[d], 1);
    int idx = roff[d] + pos;
    int2 ed; ed.x = s; ed.y = __float_as_int(dinv[s] * dinv[d]);
    cedge[idx] = ed;
}

// transpose + bf16-convert + swizzle layer weights WT[n][k]=W[k][n] (256B rows),
// and Wx -> WxT[n][k0..63] zero-padded (128B rows), with bias folded at k=40.
__global__ void k_wtrans(const float* __restrict__ Wg, const float* __restrict__ Wx,
                         const float* __restrict__ bx,
                         char* __restrict__ wt, char* __restrict__ wxt) {
    int idx = blockIdx.x * 256 + threadIdx.x;
    if (idx < NLAYERS * 16384) {
        int l = idx >> 14;
        int rem = idx & 16383;
        int n = rem >> 7;
        int k = rem & 127;
        float v = Wg[l * 16384 + k * 128 + n];
        char* img = wt + l * 32768;
        *(unsigned short*)(img + (n << 8) + ((k << 1) ^ ((n & 7) << 4))) = (unsigned short)f2bf(v);
    } else if (idx < NLAYERS * 16384 + 8192) {
        int j = idx - NLAYERS * 16384;
        int n = j >> 6;
        int k = j & 63;
        float v = (k < 40) ? Wx[k * 128 + n] : (k == 40 ? bx[n] : 0.f);
        *(unsigned short*)(wxt + (n << 7) + ((k << 1) ^ ((n & 7) << 4))) = (unsigned short)f2bf(v);
    }
}

// ---------------- input projection (MFMA): h0 = bf16(x @ Wx + bx) ----------------

__global__ __launch_bounds__(256) void k_inproj(const float* __restrict__ x,
                                                const char* __restrict__ wxt,
                                                unsigned short* __restrict__ out) {
    __shared__ char As[16384];   // 128 rows * 128 B
    const int tid = threadIdx.x;
    const int m0 = blockIdx.x << 7;

    { // stage A: 16 threads per row cover k 0..63 (4 each); k=40 -> 1.0
        const int kq = (tid & 15) << 2;   // 0,4,...,60
        const int r0 = tid >> 4;          // 0..15
        #pragma unroll
        for (int it = 0; it < 8; ++it) {
            const int r = r0 + (it << 4);
            const int grow = m0 + r;
            float x0 = 0.f, x1 = 0.f, x2 = 0.f, x3 = 0.f;
            if (grow < NNODES) {
                if (kq < 40) {
                    const float4 v = *(const float4*)(x + (size_t)grow * 40 + kq);
                    x0 = v.x; x1 = v.y; x2 = v.z; x3 = v.w;
                } else if (kq == 40) {
                    x0 = 1.0f;   // homogeneous coordinate -> bias via MFMA
                }
            }
            uint2 p;
            p.x = f2bf(x0) | (f2bf(x1) << 16);
            p.y = f2bf(x2) | (f2bf(x3) << 16);
            *(uint2*)(As + (r << 7) + ((kq << 1) ^ ((r & 7) << 4))) = p;
        }
    }
    __syncthreads();

    const int lane = tid & 63;
    const int wid = tid >> 6;
    const int l15 = lane & 15;
    const int lq = lane >> 4;

    const f32x4 zero = {0.f, 0.f, 0.f, 0.f};
    f32x4 acc[2][8];
    #pragma unroll
    for (int i = 0; i < 2; ++i)
        #pragma unroll
        for (int j = 0; j < 8; ++j) acc[i][j] = zero;

    #pragma unroll
    for (int kk = 0; kk < 2; ++kk) {
        const int kb = (kk << 6) + (lq << 4);
        short8 afr[2];
        #pragma unroll
        for (int rt = 0; rt < 2; ++rt) {
            const int r = (wid << 5) + (rt << 4) + l15;
            afr[rt] = *(const short8*)(As + (r << 7) + (kb ^ ((r & 7) << 4)));
        }
        #pragma unroll
        for (int ct = 0; ct < 8; ++ct) {
            const int n = (ct << 4) + l15;
            const short8 bfr = *(const short8*)(wxt + (n << 7) + (kb ^ ((n & 7) << 4)));
            acc[0][ct] = __builtin_amdgcn_mfma_f32_16x16x32_bf16(bfr, afr[0], acc[0][ct], 0, 0, 0);
            acc[1][ct] = __builtin_amdgcn_mfma_f32_16x16x32_bf16(bfr, afr[1], acc[1][ct], 0, 0, 0);
        }
    }

    #pragma unroll
    for (int rt = 0; rt < 2; ++rt) {
        const int grow = m0 + (wid << 5) + (rt << 4) + l15;   // node
        if (grow < NNODES) {
            #pragma unroll
            for (int ct = 0; ct < 8; ++ct) {
                uint2 pk;
                pk.x = f2bf(acc[rt][ct][0]) | (f2bf(acc[rt][ct][1]) << 16);
                pk.y = f2bf(acc[rt][ct][2]) | (f2bf(acc[rt][ct][3]) << 16);
                *(uint2*)(out + (size_t)grow * 128 + (ct << 4) + (lq << 2)) = pk;
            }
        }
    }
}

// ---------------- per-layer GEMM: xw(bf16) = BNrelu(in_bf16) @ Wg[l] ----------------
// Grid 512 = 2 blocks/CU exactly resident (no launch tail). Each block stages B
// once via global_load_lds, then grid-strides over A tiles.

__global__ __launch_bounds__(256) void k_gemm(const unsigned short* __restrict__ in,
                                              const char* __restrict__ wt,
                                              unsigned short* __restrict__ out,
                                              const float* __restrict__ statsPrev,
                                              const float* __restrict__ gamma,
                                              const float* __restrict__ beta,
                                              int apply_bn) {
    __shared__ char As[32768];   // A tile, swizzled 256B rows
    __shared__ char Bs[32768];   // W^T image copy

    const int tid = threadIdx.x;
    const int lane = tid & 63;
    const int wid = tid >> 6;
    const int l15 = lane & 15;
    const int lq = lane >> 4;

    { // stage B once: 32 chunks of 1KB, wave-linear global_load_lds
        #pragma unroll
        for (int i = 0; i < 8; ++i) {
            const int chunk = ((i << 2) + wid) << 10;   // (i*4 + wave) * 1024
            __builtin_amdgcn_global_load_lds(
                (const __attribute__((address_space(1))) unsigned int*)(wt + chunk + (lane << 4)),
                (__attribute__((address_space(3))) unsigned int*)(Bs + chunk),
                16, 0, 0);
        }
    }
    // BN coeffs (tile-invariant)
    const int c0 = (tid & 31) << 2;
    float scv[4] = {1.f, 1.f, 1.f, 1.f};
    float shv[4] = {0.f, 0.f, 0.f, 0.f};
    if (apply_bn) {
        #pragma unroll
        for (int j = 0; j < 4; ++j) {
            const float m = statsPrev[c0 + j] * INV_N;
            const float var = statsPrev[128 + c0 + j] * INV_N - m * m;
            const float s = gamma[c0 + j] * rsqrtf(var + BN_EPS);
            scv[j] = s;
            shv[j] = fmaf(-m, s, beta[c0 + j]);
        }
    }

    for (int tile = blockIdx.x; tile < NTILES; tile += gridDim.x) {
        const int m0 = tile << 7;
        { // stage A: load bf16, BN+relu in fp32, back to bf16, swizzled ds_write
            const int r0 = tid >> 5;
            #pragma unroll
            for (int it = 0; it < 16; ++it) {
                const int r = r0 + (it << 3);
                const int grow = m0 + r;
                uint2 p = {0u, 0u};
                if (grow < NNODES) {
                    const uint2 raw = *(const uint2*)(in + (size_t)grow * 128 + c0);
                    if (apply_bn) {
                        float x0 = fmaxf(fmaf(bf2f(raw.x & 0xffffu), scv[0], shv[0]), 0.f);
                        float x1 = fmaxf(fmaf(bf2f(raw.x >> 16),     scv[1], shv[1]), 0.f);
                        float x2 = fmaxf(fmaf(bf2f(raw.y & 0xffffu), scv[2], shv[2]), 0.f);
                        float x3 = fmaxf(fmaf(bf2f(raw.y >> 16),     scv[3], shv[3]), 0.f);
                        p.x = f2bf(x0) | (f2bf(x1) << 16);
                        p.y = f2bf(x2) | (f2bf(x3) << 16);
                    } else {
                        p = raw;   // already bf16
                    }
                }
                *(uint2*)(As + (r << 8) + ((c0 << 1) ^ ((r & 7) << 4))) = p;
            }
        }
        __syncthreads();   // first iter also drains B DMA (vmcnt)

        const f32x4 zero = {0.f, 0.f, 0.f, 0.f};
        f32x4 acc[2][8];
        #pragma unroll
        for (int i = 0; i < 2; ++i)
            #pragma unroll
            for (int j = 0; j < 8; ++j) acc[i][j] = zero;

        #pragma unroll
        for (int kk = 0; kk < 4; ++kk) {
            const int kb = (kk << 6) + (lq << 4);
            short8 afr[2];
            #pragma unroll
            for (int rt = 0; rt < 2; ++rt) {
                const int r = (wid << 5) + (rt << 4) + l15;
                afr[rt] = *(const short8*)(As + (r << 8) + (kb ^ ((r & 7) << 4)));
            }
            #pragma unroll
            for (int ct = 0; ct < 8; ++ct) {
                const int n = (ct << 4) + l15;
                const short8 bfr = *(const short8*)(Bs + (n << 8) + (kb ^ ((n & 7) << 4)));
                // swapped operands: D[channel][node]
                acc[0][ct] = __builtin_amdgcn_mfma_f32_16x16x32_bf16(bfr, afr[0], acc[0][ct], 0, 0, 0);
                acc[1][ct] = __builtin_amdgcn_mfma_f32_16x16x32_bf16(bfr, afr[1], acc[1][ct], 0, 0, 0);
            }
        }

        #pragma unroll
        for (int rt = 0; rt < 2; ++rt) {
            const int grow = m0 + (wid << 5) + (rt << 4) + l15;   // node
            if (grow < NNODES) {
                #pragma unroll
                for (int ct = 0; ct < 8; ++ct) {
                    uint2 pk;
                    pk.x = f2bf(acc[rt][ct][0]) | (f2bf(acc[rt][ct][1]) << 16);
                    pk.y = f2bf(acc[rt][ct][2]) | (f2bf(acc[rt][ct][3]) << 16);
                    *(uint2*)(out + (size_t)grow * 128 + (ct << 4) + (lq << 2)) = pk;
                }
            }
        }
        __syncthreads();   // protect As before next tile's stage
    }
}

// ------- aggregation: agg_l = bg + BNrelu(prev) + D^-1/2 A D^-1/2 xw ; fused BN stats -------
// R6-exact structure: 4 nodes/wave (16 lanes x 8ch); self-term via early selfu/dinv
// loads (outside the roff->cedge->gather chain); batch-4 dup-padded edge loop;
// grid 2048 (= 8 blocks/CU, exact residency). Inline BN from raw stats.

__global__ __launch_bounds__(256) void k_agg(const unsigned short* __restrict__ prev,
                                             const unsigned short* __restrict__ xw,
                                             const float* __restrict__ dinv,
                                             const int* __restrict__ roff,
                                             const int2* __restrict__ cedge,
                                             const float* __restrict__ bg,
                                             const float* __restrict__ statsPrev,
                                             const float* __restrict__ gamma,
                                             const float* __restrict__ beta,
                                             int apply_bn,
                                             unsigned short* __restrict__ outb,
                                             float* __restrict__ statsOut) {
    const int lane = threadIdx.x & 63;
    const int wv   = threadIdx.x >> 6;       // wave 0..3
    const int g16  = lane >> 4;              // node slot within wave 0..3
    const int l16  = lane & 15;
    const int c8   = l16 << 3;               // channel base (8 channels per lane)

    float sc[8], sh[8], bgv[8];
    #pragma unroll
    for (int j = 0; j < 8; ++j) {
        if (apply_bn) {
            const float m = statsPrev[c8 + j] * INV_N;
            const float var = statsPrev[128 + c8 + j] * INV_N - m * m;
            const float s = gamma[c8 + j] * rsqrtf(var + BN_EPS);
            sc[j] = s;
            sh[j] = fmaf(-m, s, beta[c8 + j]);
        } else { sc[j] = 1.f; sh[j] = 0.f; }
        bgv[j] = bg[c8 + j];
    }
    float s_[8], q_[8];
    #pragma unroll
    for (int j = 0; j < 8; ++j) { s_[j] = 0.f; q_[j] = 0.f; }

    const int stride = gridDim.x * 16;
    for (int v = blockIdx.x * 16 + wv * 4 + g16; v < NNODES; v += stride) {
        const int rof0 = roff[v];
        const int rof1 = roff[v + 1];
        const float dv = dinv[v];
        const uint4 resu  = *(const uint4*)(prev + (size_t)v * 128 + c8);
        const uint4 selfu = *(const uint4*)(xw + (size_t)v * 128 + c8);
        float a[8];
        {
            float r[8];
            r[0] = bf2f(resu.x & 0xffffu); r[1] = bf2f(resu.x >> 16);
            r[2] = bf2f(resu.y & 0xffffu); r[3] = bf2f(resu.y >> 16);
            r[4] = bf2f(resu.z & 0xffffu); r[5] = bf2f(resu.z >> 16);
            r[6] = bf2f(resu.w & 0xffffu); r[7] = bf2f(resu.w >> 16);
            if (apply_bn) {
                #pragma unroll
                for (int j = 0; j < 8; ++j)
                    a[j] = bgv[j] + fmaxf(fmaf(r[j], sc[j], sh[j]), 0.f);
            } else {
                #pragma unroll
                for (int j = 0; j < 8; ++j) a[j] = bgv[j] + r[j];
            }
            acc8(a, dv * dv, selfu);
        }
        int e = rof0;
        while (e < rof1) {
            const int rem = rof1 - e;
            const int2 d0 = cedge[e];
            const int2 d1 = cedge[rem > 1 ? e + 1 : e];
            const int2 d2 = cedge[rem > 2 ? e + 2 : e];
            const int2 d3 = cedge[rem > 3 ? e + 3 : e];
            const float w0 = __int_as_float(d0.y);
            const float w1 = rem > 1 ? __int_as_float(d1.y) : 0.f;
            const float w2 = rem > 2 ? __int_as_float(d2.y) : 0.f;
            const float w3 = rem > 3 ? __int_as_float(d3.y) : 0.f;
            const uint4 g0 = *(const uint4*)(xw + (size_t)d0.x * 128 + c8);
            const uint4 g1 = *(const uint4*)(xw + (size_t)d1.x * 128 + c8);
            const uint4 g2 = *(const uint4*)(xw + (size_t)d2.x * 128 + c8);
            const uint4 g3 = *(const uint4*)(xw + (size_t)d3.x * 128 + c8);
            acc8(a, w0, g0);
            acc8(a, w1, g1);
            acc8(a, w2, g2);
            acc8(a, w3, g3);
            e += 4;
        }
        uint4 o;
        o.x = f2bf(a[0]) | (f2bf(a[1]) << 16);
        o.y = f2bf(a[2]) | (f2bf(a[3]) << 16);
        o.z = f2bf(a[4]) | (f2bf(a[5]) << 16);
        o.w = f2bf(a[6]) | (f2bf(a[7]) << 16);
        *(uint4*)(outb + (size_t)v * 128 + c8) = o;
        #pragma unroll
        for (int j = 0; j < 8; ++j) {
            s_[j] += a[j];
            q_[j] = fmaf(a[j], a[j], q_[j]);
        }
    }

    // combine the 4 node-slots (channels depend on l16 only)
    #pragma unroll
    for (int j = 0; j < 8; ++j) {
        s_[j] += __shfl_xor(s_[j], 16); s_[j] += __shfl_xor(s_[j], 32);
        q_[j] += __shfl_xor(q_[j], 16); q_[j] += __shfl_xor(q_[j], 32);
    }
    __shared__ float red[512];
    if (g16 == 0) {
        #pragma unroll
        for (int j = 0; j < 8; ++j) red[wv * 128 + c8 + j] = s_[j];
    }
    __syncthreads();
    if (threadIdx.x < 128) {
        const int ch = threadIdx.x;
        atomicAdd(&statsOut[ch], red[ch] + red[128 + ch] + red[256 + ch] + red[384 + ch]);
    }
    __syncthreads();
    if (g16 == 0) {
        #pragma unroll
        for (int j = 0; j < 8; ++j) red[wv * 128 + c8 + j] = q_[j];
    }
    __syncthreads();
    if (threadIdx.x < 128) {
        const int ch = threadIdx.x;
        atomicAdd(&statsOut[128 + ch], red[ch] + red[128 + ch] + red[256 + ch] + red[384 + ch]);
    }
}

// ---------------- pooling (sorted batch ranges) + readout MLP ----------------

__global__ __launch_bounds__(128) void k_pool(const unsigned short* __restrict__ agg,
                                              const float* __restrict__ stats4,
                                              const float* __restrict__ gamma4,
                                              const float* __restrict__ beta4,
                                              const int* __restrict__ gstart,
                                              const float* __restrict__ W1, const float* __restrict__ b1,
                                              const float* __restrict__ W2, const float* __restrict__ b2,
                                              const float* __restrict__ W3, const float* __restrict__ b3,
                                              float* __restrict__ out) {
    __shared__ float mol[128];
    __shared__ float h1s[128];
    const int g = blockIdx.x;
    const int c = threadIdx.x;
    const float m = stats4[c] * INV_N;
    const float var = stats4[128 + c] * INV_N - m * m;
    const float sc = gamma4[c] * rsqrtf(var + BN_EPS);
    const float sh = fmaf(-m, sc, beta4[c]);
    const int v0 = gstart[g], v1 = gstart[g + 1];
    float acc = 0.f;
    for (int v = v0; v < v1; ++v)
        acc += fmaf(bf2f(agg[(size_t)v * 128 + c]), sc, sh);  // last layer: BN, no relu
    mol[c] = acc;
    __syncthreads();
    float a1 = b1[c];
    #pragma unroll 8
    for (int k = 0; k < 128; ++k) a1 = fmaf(mol[k], W1[k * 128 + c], a1);
    h1s[c] = fmaxf(a1, 0.f);
    __syncthreads();
    if (c < 64) {
        float a2 = b2[c];
        #pragma unroll 8
        for (int k = 0; k < 128; ++k) a2 = fmaf(h1s[k], W2[k * 64 + c], a2);
        float p = fmaxf(a2, 0.f) * W3[c];
        #pragma unroll
        for (int o = 32; o > 0; o >>= 1) p += __shfl_down(p, o);
        if (c == 0) out[g] = p + b3[0];
    }
}

// ---------------- launch ----------------

extern "C" void kernel_launch(void* const* d_in, const int* in_sizes, int n_in,
                              void* d_out, int out_size, void* d_ws, size_t ws_size,
                              hipStream_t stream) {
    (void)in_sizes; (void)n_in; (void)out_size; (void)ws_size;
    const float* x     = (const float*)d_in[0];
    const int*   ei    = (const int*)d_in[1];
    const int*   batch = (const int*)d_in[2];
    const float* Wx    = (const float*)d_in[3];
    const float* bx    = (const float*)d_in[4];
    const float* Wg    = (const float*)d_in[5];
    const float* bg    = (const float*)d_in[6];
    const float* gamma = (const float*)d_in[7];
    const float* beta  = (const float*)d_in[8];
    const float* W1    = (const float*)d_in[9];
    const float* b1    = (const float*)d_in[10];
    const float* W2    = (const float*)d_in[11];
    const float* b2    = (const float*)d_in[12];
    const float* W3    = (const float*)d_in[13];
    const float* b3    = (const float*)d_in[14];
    float* out = (float*)d_out;

    char* ws = (char*)d_ws;
    size_t off = 0;
    auto alloc = [&](size_t bytes) -> char* {
        char* p = ws + off;
        off += (bytes + 255) & ~(size_t)255;
        return p;
    };
    unsigned short* aggA   = (unsigned short*)alloc((size_t)NNODES * 128 * 2);
    unsigned short* aggB   = (unsigned short*)alloc((size_t)NNODES * 128 * 2);
    unsigned short* xw     = (unsigned short*)alloc((size_t)NNODES * 128 * 2);
    float*          dinv   = (float*)alloc((size_t)NNODES * 4);
    int*            cnt    = (int*)alloc((size_t)NNODES * 4);
    int*            cursor = (int*)alloc((size_t)NNODES * 4);
    int*            roff   = (int*)alloc((size_t)(NNODES + 1) * 4);
    int2*           cedge  = (int2*)alloc((size_t)(NEDGES + 4) * 8);
    char*           wt     = alloc((size_t)NLAYERS * 32768);
    char*           wxt    = alloc((size_t)16384);
    float*          stats  = (float*)alloc((size_t)NLAYERS * 256 * 4);
    int*            gstart = (int*)alloc((size_t)(NGRAPHS + 1) * 4);
    int*            bsum   = (int*)alloc((size_t)1024 * 4);

    const int NB = (NNODES + 255) / 256;   // 782
    const int EB = (NEDGES + 255) / 256;   // 1563
    const int WB = (NLAYERS * 16384 + 8192 + 255) / 256;

    k_init<<<NB, 256, 0, stream>>>(cnt, cursor, stats);
    k_count<<<EB, 256, 0, stream>>>(ei, cnt);
    k_scan1<<<NB, 256, 0, stream>>>(cnt, roff, bsum, batch, gstart);
    k_scan2<<<1, 1024, 0, stream>>>(bsum, NB);
    k_scan3<<<NB, 256, 0, stream>>>(roff, bsum, cnt, dinv);
    k_fill<<<EB, 256, 0, stream>>>(ei, dinv, roff, cursor, cedge);
    k_wtrans<<<WB, 256, 0, stream>>>(Wg, Wx, bx, wt, wxt);
    k_inproj<<<NTILES, 256, 0, stream>>>(x, wxt, aggA);

    unsigned short* cur = aggA;
    unsigned short* nxt = aggB;
    for (int l = 0; l < NLAYERS; ++l) {
        const float* sp = (l > 0) ? (stats + (l - 1) * 256) : (const float*)nullptr;
        const float* gp = (l > 0) ? (gamma + (l - 1) * 128) : (const float*)nullptr;
        const float* bp = (l > 0) ? (beta + (l - 1) * 128) : (const float*)nullptr;
        k_gemm<<<512, 256, 0, stream>>>(cur, wt + (size_t)l * 32768, xw, sp, gp, bp, l > 0);
        k_agg<<<2048, 256, 0, stream>>>(cur, xw, dinv, roff, cedge, bg + l * 128,
                                        sp, gp, bp, l > 0, nxt, stats + l * 256);
        unsigned short* t = cur; cur = nxt; nxt = t;
    }

    k_pool<<<NGRAPHS, 128, 0, stream>>>(cur, stats + 4 * 256, gamma + 4 * 128, beta + 4 * 128,
                                        gstart, W1, b1, W2, b2, W3, b3, out);
}

// Round 11
// 769.328 us; speedup vs baseline: 1.2468x; 1.1267x over previous
//
#include <hip/hip_runtime.h>
#include <stdint.h>

#define NNODES  200000
#define NEDGES  400000
#define NGRAPHS 4000
#define NLAYERS 5
#define BN_EPS  1e-5f
#define INV_N   (1.0f / (float)NNODES)
#define NTILES  ((NNODES + 127) / 128)   // 1563

typedef __attribute__((ext_vector_type(8))) short short8;
typedef __attribute__((ext_vector_type(4))) float f32x4;

__device__ __forceinline__ unsigned int f2bf(float f) {
    unsigned int u = __float_as_uint(f);
    return (u + 0x7fffu + ((u >> 16) & 1u)) >> 16;
}
__device__ __forceinline__ float bf2f(unsigned int b) {
    return __uint_as_float(b << 16);
}

__device__ __forceinline__ void acc8(float (&a)[8], float wgt, const uint4& g) {
    a[0] = fmaf(wgt, bf2f(g.x & 0xffffu), a[0]);
    a[1] = fmaf(wgt, bf2f(g.x >> 16),     a[1]);
    a[2] = fmaf(wgt, bf2f(g.y & 0xffffu), a[2]);
    a[3] = fmaf(wgt, bf2f(g.y >> 16),     a[3]);
    a[4] = fmaf(wgt, bf2f(g.z & 0xffffu), a[4]);
    a[5] = fmaf(wgt, bf2f(g.z >> 16),     a[5]);
    a[6] = fmaf(wgt, bf2f(g.w & 0xffffu), a[6]);
    a[7] = fmaf(wgt, bf2f(g.w >> 16),     a[7]);
}

// ---------------- graph prep ----------------

__global__ void k_init(int* __restrict__ cnt, int* __restrict__ cursor,
                       float* __restrict__ stats) {
    int i = blockIdx.x * 256 + threadIdx.x;
    if (i < NNODES) { cnt[i] = 0; cursor[i] = 0; }
    if (i < NLAYERS * 256) stats[i] = 0.f;
}

__global__ void k_count(const int* __restrict__ ei, int* __restrict__ cnt) {
    int e = blockIdx.x * 256 + threadIdx.x;
    if (e < NEDGES) atomicAdd(&cnt[ei[NEDGES + e]], 1);
}

// block-scan of cnt (real edges only); also graph ranges from sorted batch
__global__ __launch_bounds__(256) void k_scan1(const int* __restrict__ cnt,
                                               int* __restrict__ roff, int* __restrict__ bsum,
                                               const int* __restrict__ batch,
                                               int* __restrict__ gstart) {
    __shared__ int s[256];
    int t = threadIdx.x;
    int v = blockIdx.x * 256 + t;
    int val = (v < NNODES) ? cnt[v] : 0;
    s[t] = val; __syncthreads();
    int sum = val;
    for (int o = 1; o < 256; o <<= 1) {
        int tmp = (t >= o) ? s[t - o] : 0;
        __syncthreads();
        sum += tmp; s[t] = sum;
        __syncthreads();
    }
    if (v < NNODES) roff[v] = sum - val;       // exclusive within block
    if (t == 255) bsum[blockIdx.x] = s[255];

    if (v < NNODES) {   // graph ranges (merged k_ranges)
        int b = batch[v];
        if (v == 0) {
            for (int g = 0; g <= b; ++g) gstart[g] = 0;
        } else {
            int pb = batch[v - 1];
            for (int g = pb + 1; g <= b; ++g) gstart[g] = v;
        }
        if (v == NNODES - 1) {
            for (int g = b + 1; g <= NGRAPHS; ++g) gstart[g] = NNODES;
        }
    }
}

__global__ __launch_bounds__(1024) void k_scan2(int* __restrict__ bsum, int nb) {
    __shared__ int s[1024];
    int t = threadIdx.x;
    int val = (t < nb) ? bsum[t] : 0;
    s[t] = val; __syncthreads();
    int sum = val;
    for (int o = 1; o < 1024; o <<= 1) {
        int tmp = (t >= o) ? s[t - o] : 0;
        __syncthreads();
        sum += tmp; s[t] = sum;
        __syncthreads();
    }
    if (t < nb) bsum[t] = sum - val;           // exclusive block offsets
}

// finalize roff; compute dinv
__global__ void k_scan3(int* __restrict__ roff, const int* __restrict__ bsum,
                        const int* __restrict__ cnt, float* __restrict__ dinv) {
    int v = blockIdx.x * 256 + threadIdx.x;
    if (v < NNODES) {
        roff[v] += bsum[blockIdx.x];
        dinv[v] = rsqrtf((float)cnt[v] + 1.0f);
    }
    if (v == 0) roff[NNODES] = NEDGES;
}

__global__ void k_fill(const int* __restrict__ ei, const float* __restrict__ dinv,
                       const int* __restrict__ roff, int* __restrict__ cursor,
                       int2* __restrict__ cedge) {
    int e = blockIdx.x * 256 + threadIdx.x;
    if (e >= NEDGES) return;
    int s = ei[e], d = ei[NEDGES + e];
    int pos = atomicAdd(&cursor[d], 1);
    int idx = roff[d] + pos;
    int2 ed; ed.x = s; ed.y = __float_as_int(dinv[s] * dinv[d]);
    cedge[idx] = ed;
}

// transpose + bf16-convert + swizzle layer weights WT[n][k]=W[k][n] (256B rows),
// and Wx -> WxT[n][k0..63] zero-padded (128B rows), with bias folded at k=40.
__global__ void k_wtrans(const float* __restrict__ Wg, const float* __restrict__ Wx,
                         const float* __restrict__ bx,
                         char* __restrict__ wt, char* __restrict__ wxt) {
    int idx = blockIdx.x * 256 + threadIdx.x;
    if (idx < NLAYERS * 16384) {
        int l = idx >> 14;
        int rem = idx & 16383;
        int n = rem >> 7;
        int k = rem & 127;
        float v = Wg[l * 16384 + k * 128 + n];
        char* img = wt + l * 32768;
        *(unsigned short*)(img + (n << 8) + ((k << 1) ^ ((n & 7) << 4))) = (unsigned short)f2bf(v);
    } else if (idx < NLAYERS * 16384 + 8192) {
        int j = idx - NLAYERS * 16384;
        int n = j >> 6;
        int k = j & 63;
        float v = (k < 40) ? Wx[k * 128 + n] : (k == 40 ? bx[n] : 0.f);
        *(unsigned short*)(wxt + (n << 7) + ((k << 1) ^ ((n & 7) << 4))) = (unsigned short)f2bf(v);
    }
}

// BN finalize: per-channel scale/shift from raw stats (tiny kernel, 1 block)
__global__ void k_bnfin(const float* __restrict__ stats, const float* __restrict__ gamma,
                        const float* __restrict__ beta, float* __restrict__ sc,
                        float* __restrict__ sh) {
    int c = threadIdx.x;
    float mean = stats[c] * INV_N;
    float var = stats[128 + c] * INV_N - mean * mean;
    float s = gamma[c] * rsqrtf(var + BN_EPS);
    sc[c] = s;
    sh[c] = fmaf(-mean, s, beta[c]);
}

// ---------------- input projection (MFMA): h0 = bf16(x @ Wx + bx) ----------------

__global__ __launch_bounds__(256) void k_inproj(const float* __restrict__ x,
                                                const char* __restrict__ wxt,
                                                unsigned short* __restrict__ out) {
    __shared__ char As[16384];   // 128 rows * 128 B
    const int tid = threadIdx.x;
    const int m0 = blockIdx.x << 7;

    { // stage A: 16 threads per row cover k 0..63 (4 each); k=40 -> 1.0
        const int kq = (tid & 15) << 2;   // 0,4,...,60
        const int r0 = tid >> 4;          // 0..15
        #pragma unroll
        for (int it = 0; it < 8; ++it) {
            const int r = r0 + (it << 4);
            const int grow = m0 + r;
            float x0 = 0.f, x1 = 0.f, x2 = 0.f, x3 = 0.f;
            if (grow < NNODES) {
                if (kq < 40) {
                    const float4 v = *(const float4*)(x + (size_t)grow * 40 + kq);
                    x0 = v.x; x1 = v.y; x2 = v.z; x3 = v.w;
                } else if (kq == 40) {
                    x0 = 1.0f;   // homogeneous coordinate -> bias via MFMA
                }
            }
            uint2 p;
            p.x = f2bf(x0) | (f2bf(x1) << 16);
            p.y = f2bf(x2) | (f2bf(x3) << 16);
            *(uint2*)(As + (r << 7) + ((kq << 1) ^ ((r & 7) << 4))) = p;
        }
    }
    __syncthreads();

    const int lane = tid & 63;
    const int wid = tid >> 6;
    const int l15 = lane & 15;
    const int lq = lane >> 4;

    const f32x4 zero = {0.f, 0.f, 0.f, 0.f};
    f32x4 acc[2][8];
    #pragma unroll
    for (int i = 0; i < 2; ++i)
        #pragma unroll
        for (int j = 0; j < 8; ++j) acc[i][j] = zero;

    #pragma unroll
    for (int kk = 0; kk < 2; ++kk) {
        const int kb = (kk << 6) + (lq << 4);
        short8 afr[2];
        #pragma unroll
        for (int rt = 0; rt < 2; ++rt) {
            const int r = (wid << 5) + (rt << 4) + l15;
            afr[rt] = *(const short8*)(As + (r << 7) + (kb ^ ((r & 7) << 4)));
        }
        #pragma unroll
        for (int ct = 0; ct < 8; ++ct) {
            const int n = (ct << 4) + l15;
            const short8 bfr = *(const short8*)(wxt + (n << 7) + (kb ^ ((n & 7) << 4)));
            acc[0][ct] = __builtin_amdgcn_mfma_f32_16x16x32_bf16(bfr, afr[0], acc[0][ct], 0, 0, 0);
            acc[1][ct] = __builtin_amdgcn_mfma_f32_16x16x32_bf16(bfr, afr[1], acc[1][ct], 0, 0, 0);
        }
    }

    #pragma unroll
    for (int rt = 0; rt < 2; ++rt) {
        const int grow = m0 + (wid << 5) + (rt << 4) + l15;   // node
        if (grow < NNODES) {
            #pragma unroll
            for (int ct = 0; ct < 8; ++ct) {
                uint2 pk;
                pk.x = f2bf(acc[rt][ct][0]) | (f2bf(acc[rt][ct][1]) << 16);
                pk.y = f2bf(acc[rt][ct][2]) | (f2bf(acc[rt][ct][3]) << 16);
                *(uint2*)(out + (size_t)grow * 128 + (ct << 4) + (lq << 2)) = pk;
            }
        }
    }
}

// ---------------- per-layer GEMM: xw(bf16) = BNrelu(in_bf16) @ Wg[l] ----------------
// Grid 512 = 2 blocks/CU exactly resident. B staged once per block via
// global_load_lds; grid-stride over A tiles; A-stage widened to uint4 (16B).

__global__ __launch_bounds__(256) void k_gemm(const unsigned short* __restrict__ in,
                                              const char* __restrict__ wt,
                                              unsigned short* __restrict__ out,
                                              const float* __restrict__ bnsc,
                                              const float* __restrict__ bnsh,
                                              int apply_bn) {
    __shared__ char As[32768];   // A tile, swizzled 256B rows
    __shared__ char Bs[32768];   // W^T image copy

    const int tid = threadIdx.x;
    const int lane = tid & 63;
    const int wid = tid >> 6;
    const int l15 = lane & 15;
    const int lq = lane >> 4;

    { // stage B once: 32 chunks of 1KB, wave-linear global_load_lds
        #pragma unroll
        for (int i = 0; i < 8; ++i) {
            const int chunk = ((i << 2) + wid) << 10;   // (i*4 + wave) * 1024
            __builtin_amdgcn_global_load_lds(
                (const __attribute__((address_space(1))) unsigned int*)(wt + chunk + (lane << 4)),
                (__attribute__((address_space(3))) unsigned int*)(Bs + chunk),
                16, 0, 0);
        }
    }
    // BN coeffs (tile-invariant), 8 channels per thread
    const int c0 = (tid & 15) << 3;
    float scv[8], shv[8];
    #pragma unroll
    for (int j = 0; j < 8; ++j) {
        scv[j] = apply_bn ? bnsc[c0 + j] : 1.f;
        shv[j] = apply_bn ? bnsh[c0 + j] : 0.f;
    }

    for (int tile = blockIdx.x; tile < NTILES; tile += gridDim.x) {
        const int m0 = tile << 7;
        { // stage A: uint4 load, BN+relu in fp32, uint4 swizzled ds_write
            const int r0 = tid >> 4;   // 0..15
            #pragma unroll
            for (int it = 0; it < 8; ++it) {
                const int r = r0 + (it << 4);
                const int grow = m0 + r;
                uint4 p = {0u, 0u, 0u, 0u};
                if (grow < NNODES) {
                    const uint4 raw = *(const uint4*)(in + (size_t)grow * 128 + c0);
                    if (apply_bn) {
                        float e0 = fmaxf(fmaf(bf2f(raw.x & 0xffffu), scv[0], shv[0]), 0.f);
                        float e1 = fmaxf(fmaf(bf2f(raw.x >> 16),     scv[1], shv[1]), 0.f);
                        float e2 = fmaxf(fmaf(bf2f(raw.y & 0xffffu), scv[2], shv[2]), 0.f);
                        float e3 = fmaxf(fmaf(bf2f(raw.y >> 16),     scv[3], shv[3]), 0.f);
                        float e4 = fmaxf(fmaf(bf2f(raw.z & 0xffffu), scv[4], shv[4]), 0.f);
                        float e5 = fmaxf(fmaf(bf2f(raw.z >> 16),     scv[5], shv[5]), 0.f);
                        float e6 = fmaxf(fmaf(bf2f(raw.w & 0xffffu), scv[6], shv[6]), 0.f);
                        float e7 = fmaxf(fmaf(bf2f(raw.w >> 16),     scv[7], shv[7]), 0.f);
                        p.x = f2bf(e0) | (f2bf(e1) << 16);
                        p.y = f2bf(e2) | (f2bf(e3) << 16);
                        p.z = f2bf(e4) | (f2bf(e5) << 16);
                        p.w = f2bf(e6) | (f2bf(e7) << 16);
                    } else {
                        p = raw;   // already bf16
                    }
                }
                *(uint4*)(As + (r << 8) + ((c0 << 1) ^ ((r & 7) << 4))) = p;
            }
        }
        __syncthreads();   // first iter also drains B DMA (vmcnt)

        const f32x4 zero = {0.f, 0.f, 0.f, 0.f};
        f32x4 acc[2][8];
        #pragma unroll
        for (int i = 0; i < 2; ++i)
            #pragma unroll
            for (int j = 0; j < 8; ++j) acc[i][j] = zero;

        #pragma unroll
        for (int kk = 0; kk < 4; ++kk) {
            const int kb = (kk << 6) + (lq << 4);
            short8 afr[2];
            #pragma unroll
            for (int rt = 0; rt < 2; ++rt) {
                const int r = (wid << 5) + (rt << 4) + l15;
                afr[rt] = *(const short8*)(As + (r << 8) + (kb ^ ((r & 7) << 4)));
            }
            #pragma unroll
            for (int ct = 0; ct < 8; ++ct) {
                const int n = (ct << 4) + l15;
                const short8 bfr = *(const short8*)(Bs + (n << 8) + (kb ^ ((n & 7) << 4)));
                // swapped operands: D[channel][node]
                acc[0][ct] = __builtin_amdgcn_mfma_f32_16x16x32_bf16(bfr, afr[0], acc[0][ct], 0, 0, 0);
                acc[1][ct] = __builtin_amdgcn_mfma_f32_16x16x32_bf16(bfr, afr[1], acc[1][ct], 0, 0, 0);
            }
        }

        #pragma unroll
        for (int rt = 0; rt < 2; ++rt) {
            const int grow = m0 + (wid << 5) + (rt << 4) + l15;   // node
            if (grow < NNODES) {
                #pragma unroll
                for (int ct = 0; ct < 8; ++ct) {
                    uint2 pk;
                    pk.x = f2bf(acc[rt][ct][0]) | (f2bf(acc[rt][ct][1]) << 16);
                    pk.y = f2bf(acc[rt][ct][2]) | (f2bf(acc[rt][ct][3]) << 16);
                    *(uint2*)(out + (size_t)grow * 128 + (ct << 4) + (lq << 2)) = pk;
                }
            }
        }
        __syncthreads();   // protect As before next tile's stage
    }
}

// ------- aggregation: agg_l = bg + BNrelu(prev) + D^-1/2 A D^-1/2 xw ; fused BN stats -------
// R6-exact: 4 nodes/wave (16 lanes x 8ch); early selfu/dinv loads; batch-4
// dup-padded edge loop; grid 2048; precomputed bnsc/bnsh (k_bnfin).

__global__ __launch_bounds__(256) void k_agg(const unsigned short* __restrict__ prev,
                                             const unsigned short* __restrict__ xw,
                                             const float* __restrict__ dinv,
                                             const int* __restrict__ roff,
                                             const int2* __restrict__ cedge,
                                             const float* __restrict__ bg,
                                             const float* __restrict__ bnsc,
                                             const float* __restrict__ bnsh,
                                             int apply_bn,
                                             unsigned short* __restrict__ outb,
                                             float* __restrict__ statsOut) {
    const int lane = threadIdx.x & 63;
    const int wv   = threadIdx.x >> 6;       // wave 0..3
    const int g16  = lane >> 4;              // node slot within wave 0..3
    const int l16  = lane & 15;
    const int c8   = l16 << 3;               // channel base (8 channels per lane)

    float sc[8], sh[8], bgv[8];
    #pragma unroll
    for (int j = 0; j < 8; ++j) {
        sc[j] = apply_bn ? bnsc[c8 + j] : 1.f;
        sh[j] = apply_bn ? bnsh[c8 + j] : 0.f;
        bgv[j] = bg[c8 + j];
    }
    float s_[8], q_[8];
    #pragma unroll
    for (int j = 0; j < 8; ++j) { s_[j] = 0.f; q_[j] = 0.f; }

    const int stride = gridDim.x * 16;
    for (int v = blockIdx.x * 16 + wv * 4 + g16; v < NNODES; v += stride) {
        const int rof0 = roff[v];
        const int rof1 = roff[v + 1];
        const float dv = dinv[v];
        const uint4 resu  = *(const uint4*)(prev + (size_t)v * 128 + c8);
        const uint4 selfu = *(const uint4*)(xw + (size_t)v * 128 + c8);
        float a[8];
        {
            float r[8];
            r[0] = bf2f(resu.x & 0xffffu); r[1] = bf2f(resu.x >> 16);
            r[2] = bf2f(resu.y & 0xffffu); r[3] = bf2f(resu.y >> 16);
            r[4] = bf2f(resu.z & 0xffffu); r[5] = bf2f(resu.z >> 16);
            r[6] = bf2f(resu.w & 0xffffu); r[7] = bf2f(resu.w >> 16);
            if (apply_bn) {
                #pragma unroll
                for (int j = 0; j < 8; ++j)
                    a[j] = bgv[j] + fmaxf(fmaf(r[j], sc[j], sh[j]), 0.f);
            } else {
                #pragma unroll
                for (int j = 0; j < 8; ++j) a[j] = bgv[j] + r[j];
            }
            acc8(a, dv * dv, selfu);
        }
        int e = rof0;
        while (e < rof1) {
            const int rem = rof1 - e;
            const int2 d0 = cedge[e];
            const int2 d1 = cedge[rem > 1 ? e + 1 : e];
            const int2 d2 = cedge[rem > 2 ? e + 2 : e];
            const int2 d3 = cedge[rem > 3 ? e + 3 : e];
            const float w0 = __int_as_float(d0.y);
            const float w1 = rem > 1 ? __int_as_float(d1.y) : 0.f;
            const float w2 = rem > 2 ? __int_as_float(d2.y) : 0.f;
            const float w3 = rem > 3 ? __int_as_float(d3.y) : 0.f;
            const uint4 g0 = *(const uint4*)(xw + (size_t)d0.x * 128 + c8);
            const uint4 g1 = *(const uint4*)(xw + (size_t)d1.x * 128 + c8);
            const uint4 g2 = *(const uint4*)(xw + (size_t)d2.x * 128 + c8);
            const uint4 g3 = *(const uint4*)(xw + (size_t)d3.x * 128 + c8);
            acc8(a, w0, g0);
            acc8(a, w1, g1);
            acc8(a, w2, g2);
            acc8(a, w3, g3);
            e += 4;
        }
        uint4 o;
        o.x = f2bf(a[0]) | (f2bf(a[1]) << 16);
        o.y = f2bf(a[2]) | (f2bf(a[3]) << 16);
        o.z = f2bf(a[4]) | (f2bf(a[5]) << 16);
        o.w = f2bf(a[6]) | (f2bf(a[7]) << 16);
        *(uint4*)(outb + (size_t)v * 128 + c8) = o;
        #pragma unroll
        for (int j = 0; j < 8; ++j) {
            s_[j] += a[j];
            q_[j] = fmaf(a[j], a[j], q_[j]);
        }
    }

    // combine the 4 node-slots (channels depend on l16 only)
    #pragma unroll
    for (int j = 0; j < 8; ++j) {
        s_[j] += __shfl_xor(s_[j], 16); s_[j] += __shfl_xor(s_[j], 32);
        q_[j] += __shfl_xor(q_[j], 16); q_[j] += __shfl_xor(q_[j], 32);
    }
    __shared__ float red[512];
    if (g16 == 0) {
        #pragma unroll
        for (int j = 0; j < 8; ++j) red[wv * 128 + c8 + j] = s_[j];
    }
    __syncthreads();
    if (threadIdx.x < 128) {
        const int ch = threadIdx.x;
        atomicAdd(&statsOut[ch], red[ch] + red[128 + ch] + red[256 + ch] + red[384 + ch]);
    }
    __syncthreads();
    if (g16 == 0) {
        #pragma unroll
        for (int j = 0; j < 8; ++j) red[wv * 128 + c8 + j] = q_[j];
    }
    __syncthreads();
    if (threadIdx.x < 128) {
        const int ch = threadIdx.x;
        atomicAdd(&statsOut[128 + ch], red[ch] + red[128 + ch] + red[256 + ch] + red[384 + ch]);
    }
}

// ---------------- pooling (sorted batch ranges) + readout MLP ----------------

__global__ __launch_bounds__(128) void k_pool(const unsigned short* __restrict__ agg,
                                              const float* __restrict__ bnsc,
                                              const float* __restrict__ bnsh,
                                              const int* __restrict__ gstart,
                                              const float* __restrict__ W1, const float* __restrict__ b1,
                                              const float* __restrict__ W2, const float* __restrict__ b2,
                                              const float* __restrict__ W3, const float* __restrict__ b3,
                                              float* __restrict__ out) {
    __shared__ float mol[128];
    __shared__ float h1s[128];
    const int g = blockIdx.x;
    const int c = threadIdx.x;
    const float sc = bnsc[c], sh = bnsh[c];
    const int v0 = gstart[g], v1 = gstart[g + 1];
    float acc = 0.f;
    for (int v = v0; v < v1; ++v)
        acc += fmaf(bf2f(agg[(size_t)v * 128 + c]), sc, sh);  // last layer: BN, no relu
    mol[c] = acc;
    __syncthreads();
    float a1 = b1[c];
    #pragma unroll 8
    for (int k = 0; k < 128; ++k) a1 = fmaf(mol[k], W1[k * 128 + c], a1);
    h1s[c] = fmaxf(a1, 0.f);
    __syncthreads();
    if (c < 64) {
        float a2 = b2[c];
        #pragma unroll 8
        for (int k = 0; k < 128; ++k) a2 = fmaf(h1s[k], W2[k * 64 + c], a2);
        float p = fmaxf(a2, 0.f) * W3[c];
        #pragma unroll
        for (int o = 32; o > 0; o >>= 1) p += __shfl_down(p, o);
        if (c == 0) out[g] = p + b3[0];
    }
}

// ---------------- launch ----------------

extern "C" void kernel_launch(void* const* d_in, const int* in_sizes, int n_in,
                              void* d_out, int out_size, void* d_ws, size_t ws_size,
                              hipStream_t stream) {
    (void)in_sizes; (void)n_in; (void)out_size; (void)ws_size;
    const float* x     = (const float*)d_in[0];
    const int*   ei    = (const int*)d_in[1];
    const int*   batch = (const int*)d_in[2];
    const float* Wx    = (const float*)d_in[3];
    const float* bx    = (const float*)d_in[4];
    const float* Wg    = (const float*)d_in[5];
    const float* bg    = (const float*)d_in[6];
    const float* gamma = (const float*)d_in[7];
    const float* beta  = (const float*)d_in[8];
    const float* W1    = (const float*)d_in[9];
    const float* b1    = (const float*)d_in[10];
    const float* W2    = (const float*)d_in[11];
    const float* b2    = (const float*)d_in[12];
    const float* W3    = (const float*)d_in[13];
    const float* b3    = (const float*)d_in[14];
    float* out = (float*)d_out;

    char* ws = (char*)d_ws;
    size_t off = 0;
    auto alloc = [&](size_t bytes) -> char* {
        char* p = ws + off;
        off += (bytes + 255) & ~(size_t)255;
        return p;
    };
    unsigned short* aggA   = (unsigned short*)alloc((size_t)NNODES * 128 * 2);
    unsigned short* aggB   = (unsigned short*)alloc((size_t)NNODES * 128 * 2);
    unsigned short* xw     = (unsigned short*)alloc((size_t)NNODES * 128 * 2);
    float*          dinv   = (float*)alloc((size_t)NNODES * 4);
    int*            cnt    = (int*)alloc((size_t)NNODES * 4);
    int*            cursor = (int*)alloc((size_t)NNODES * 4);
    int*            roff   = (int*)alloc((size_t)(NNODES + 1) * 4);
    int2*           cedge  = (int2*)alloc((size_t)(NEDGES + 4) * 8);
    char*           wt     = alloc((size_t)NLAYERS * 32768);
    char*           wxt    = alloc((size_t)16384);
    float*          stats  = (float*)alloc((size_t)NLAYERS * 256 * 4);
    float*          bnsc   = (float*)alloc((size_t)NLAYERS * 128 * 4);
    float*          bnsh   = (float*)alloc((size_t)NLAYERS * 128 * 4);
    int*            gstart = (int*)alloc((size_t)(NGRAPHS + 1) * 4);
    int*            bsum   = (int*)alloc((size_t)1024 * 4);

    const int NB = (NNODES + 255) / 256;   // 782
    const int EB = (NEDGES + 255) / 256;   // 1563
    const int WB = (NLAYERS * 16384 + 8192 + 255) / 256;

    k_init<<<NB, 256, 0, stream>>>(cnt, cursor, stats);
    k_count<<<EB, 256, 0, stream>>>(ei, cnt);
    k_scan1<<<NB, 256, 0, stream>>>(cnt, roff, bsum, batch, gstart);
    k_scan2<<<1, 1024, 0, stream>>>(bsum, NB);
    k_scan3<<<NB, 256, 0, stream>>>(roff, bsum, cnt, dinv);
    k_fill<<<EB, 256, 0, stream>>>(ei, dinv, roff, cursor, cedge);
    k_wtrans<<<WB, 256, 0, stream>>>(Wg, Wx, bx, wt, wxt);
    k_inproj<<<NTILES, 256, 0, stream>>>(x, wxt, aggA);

    unsigned short* cur = aggA;
    unsigned short* nxt = aggB;
    for (int l = 0; l < NLAYERS; ++l) {
        const float* psc = (l > 0) ? (bnsc + (l - 1) * 128) : (const float*)nullptr;
        const float* psh = (l > 0) ? (bnsh + (l - 1) * 128) : (const float*)nullptr;
        k_gemm<<<512, 256, 0, stream>>>(cur, wt + (size_t)l * 32768, xw, psc, psh, l > 0);
        k_agg<<<2048, 256, 0, stream>>>(cur, xw, dinv, roff, cedge, bg + l * 128,
                                        psc, psh, l > 0, nxt, stats + l * 256);
        k_bnfin<<<1, 128, 0, stream>>>(stats + l * 256, gamma + l * 128, beta + l * 128,
                                       bnsc + l * 128, bnsh + l * 128);
        unsigned short* t = cur; cur = nxt; nxt = t;
    }

    k_pool<<<NGRAPHS, 128, 0, stream>>>(cur, bnsc + 4 * 128, bnsh + 4 * 128, gstart,
                                        W1, b1, W2, b2, W3, b3, out);
}

// Round 12
// 742.943 us; speedup vs baseline: 1.2911x; 1.0355x over previous
//
#include <hip/hip_runtime.h>
#include <stdint.h>

#define NNODES  200000
#define NEDGES  400000
#define NGRAPHS 4000
#define NLAYERS 5
#define BN_EPS  1e-5f
#define INV_N   (1.0f / (float)NNODES)
#define NTILES  ((NNODES + 127) / 128)   // 1563

typedef __attribute__((ext_vector_type(8))) short short8;
typedef __attribute__((ext_vector_type(4))) float f32x4;

__device__ __forceinline__ unsigned int f2bf(float f) {
    unsigned int u = __float_as_uint(f);
    return (u + 0x7fffu + ((u >> 16) & 1u)) >> 16;
}
__device__ __forceinline__ float bf2f(unsigned int b) {
    return __uint_as_float(b << 16);
}

__device__ __forceinline__ void acc8(float (&a)[8], float wgt, const uint4& g) {
    a[0] = fmaf(wgt, bf2f(g.x & 0xffffu), a[0]);
    a[1] = fmaf(wgt, bf2f(g.x >> 16),     a[1]);
    a[2] = fmaf(wgt, bf2f(g.y & 0xffffu), a[2]);
    a[3] = fmaf(wgt, bf2f(g.y >> 16),     a[3]);
    a[4] = fmaf(wgt, bf2f(g.z & 0xffffu), a[4]);
    a[5] = fmaf(wgt, bf2f(g.z >> 16),     a[5]);
    a[6] = fmaf(wgt, bf2f(g.w & 0xffffu), a[6]);
    a[7] = fmaf(wgt, bf2f(g.w >> 16),     a[7]);
}

// ---------------- graph prep ----------------

__global__ void k_init(int* __restrict__ cnt, int* __restrict__ cursor,
                       float* __restrict__ stats) {
    int i = blockIdx.x * 256 + threadIdx.x;
    if (i < NNODES) { cnt[i] = 0; cursor[i] = 0; }
    if (i < NLAYERS * 256) stats[i] = 0.f;
}

__global__ void k_count(const int* __restrict__ ei, int* __restrict__ cnt) {
    int e = blockIdx.x * 256 + threadIdx.x;
    if (e < NEDGES) atomicAdd(&cnt[ei[NEDGES + e]], 1);
}

// block-scan of cnt (real edges only); also graph ranges from sorted batch
__global__ __launch_bounds__(256) void k_scan1(const int* __restrict__ cnt,
                                               int* __restrict__ roff, int* __restrict__ bsum,
                                               const int* __restrict__ batch,
                                               int* __restrict__ gstart) {
    __shared__ int s[256];
    int t = threadIdx.x;
    int v = blockIdx.x * 256 + t;
    int val = (v < NNODES) ? cnt[v] : 0;
    s[t] = val; __syncthreads();
    int sum = val;
    for (int o = 1; o < 256; o <<= 1) {
        int tmp = (t >= o) ? s[t - o] : 0;
        __syncthreads();
        sum += tmp; s[t] = sum;
        __syncthreads();
    }
    if (v < NNODES) roff[v] = sum - val;       // exclusive within block
    if (t == 255) bsum[blockIdx.x] = s[255];

    if (v < NNODES) {   // graph ranges (merged k_ranges)
        int b = batch[v];
        if (v == 0) {
            for (int g = 0; g <= b; ++g) gstart[g] = 0;
        } else {
            int pb = batch[v - 1];
            for (int g = pb + 1; g <= b; ++g) gstart[g] = v;
        }
        if (v == NNODES - 1) {
            for (int g = b + 1; g <= NGRAPHS; ++g) gstart[g] = NNODES;
        }
    }
}

__global__ __launch_bounds__(1024) void k_scan2(int* __restrict__ bsum, int nb) {
    __shared__ int s[1024];
    int t = threadIdx.x;
    int val = (t < nb) ? bsum[t] : 0;
    s[t] = val; __syncthreads();
    int sum = val;
    for (int o = 1; o < 1024; o <<= 1) {
        int tmp = (t >= o) ? s[t - o] : 0;
        __syncthreads();
        sum += tmp; s[t] = sum;
        __syncthreads();
    }
    if (t < nb) bsum[t] = sum - val;           // exclusive block offsets
}

// finalize roff; compute dinv
__global__ void k_scan3(int* __restrict__ roff, const int* __restrict__ bsum,
                        const int* __restrict__ cnt, float* __restrict__ dinv) {
    int v = blockIdx.x * 256 + threadIdx.x;
    if (v < NNODES) {
        roff[v] += bsum[blockIdx.x];
        dinv[v] = rsqrtf((float)cnt[v] + 1.0f);
    }
    if (v == 0) roff[NNODES] = NEDGES;
}

__global__ void k_fill(const int* __restrict__ ei, const float* __restrict__ dinv,
                       const int* __restrict__ roff, int* __restrict__ cursor,
                       int2* __restrict__ cedge) {
    int e = blockIdx.x * 256 + threadIdx.x;
    if (e >= NEDGES) return;
    int s = ei[e], d = ei[NEDGES + e];
    int pos = atomicAdd(&cursor[d], 1);
    int idx = roff[d] + pos;
    int2 ed; ed.x = s; ed.y = __float_as_int(dinv[s] * dinv[d]);
    cedge[idx] = ed;
}

// transpose + bf16-convert + swizzle layer weights WT[n][k]=W[k][n] (256B rows),
// and Wx -> WxT[n][k0..63] zero-padded (128B rows), with bias folded at k=40.
__global__ void k_wtrans(const float* __restrict__ Wg, const float* __restrict__ Wx,
                         const float* __restrict__ bx,
                         char* __restrict__ wt, char* __restrict__ wxt) {
    int idx = blockIdx.x * 256 + threadIdx.x;
    if (idx < NLAYERS * 16384) {
        int l = idx >> 14;
        int rem = idx & 16383;
        int n = rem >> 7;
        int k = rem & 127;
        float v = Wg[l * 16384 + k * 128 + n];
        char* img = wt + l * 32768;
        *(unsigned short*)(img + (n << 8) + ((k << 1) ^ ((n & 7) << 4))) = (unsigned short)f2bf(v);
    } else if (idx < NLAYERS * 16384 + 8192) {
        int j = idx - NLAYERS * 16384;
        int n = j >> 6;
        int k = j & 63;
        float v = (k < 40) ? Wx[k * 128 + n] : (k == 40 ? bx[n] : 0.f);
        *(unsigned short*)(wxt + (n << 7) + ((k << 1) ^ ((n & 7) << 4))) = (unsigned short)f2bf(v);
    }
}

// BN finalize: per-channel scale/shift from raw stats (tiny kernel, 1 block)
__global__ void k_bnfin(const float* __restrict__ stats, const float* __restrict__ gamma,
                        const float* __restrict__ beta, float* __restrict__ sc,
                        float* __restrict__ sh) {
    int c = threadIdx.x;
    float mean = stats[c] * INV_N;
    float var = stats[128 + c] * INV_N - mean * mean;
    float s = gamma[c] * rsqrtf(var + BN_EPS);
    sc[c] = s;
    sh[c] = fmaf(-mean, s, beta[c]);
}

// ---------------- input projection (MFMA): h0 = bf16(x @ Wx + bx) ----------------

__global__ __launch_bounds__(256) void k_inproj(const float* __restrict__ x,
                                                const char* __restrict__ wxt,
                                                unsigned short* __restrict__ out) {
    __shared__ char As[16384];   // 128 rows * 128 B
    const int tid = threadIdx.x;
    const int m0 = blockIdx.x << 7;

    { // stage A: 16 threads per row cover k 0..63 (4 each); k=40 -> 1.0
        const int kq = (tid & 15) << 2;   // 0,4,...,60
        const int r0 = tid >> 4;          // 0..15
        #pragma unroll
        for (int it = 0; it < 8; ++it) {
            const int r = r0 + (it << 4);
            const int grow = m0 + r;
            float x0 = 0.f, x1 = 0.f, x2 = 0.f, x3 = 0.f;
            if (grow < NNODES) {
                if (kq < 40) {
                    const float4 v = *(const float4*)(x + (size_t)grow * 40 + kq);
                    x0 = v.x; x1 = v.y; x2 = v.z; x3 = v.w;
                } else if (kq == 40) {
                    x0 = 1.0f;   // homogeneous coordinate -> bias via MFMA
                }
            }
            uint2 p;
            p.x = f2bf(x0) | (f2bf(x1) << 16);
            p.y = f2bf(x2) | (f2bf(x3) << 16);
            *(uint2*)(As + (r << 7) + ((kq << 1) ^ ((r & 7) << 4))) = p;
        }
    }
    __syncthreads();

    const int lane = tid & 63;
    const int wid = tid >> 6;
    const int l15 = lane & 15;
    const int lq = lane >> 4;

    const f32x4 zero = {0.f, 0.f, 0.f, 0.f};
    f32x4 acc[2][8];
    #pragma unroll
    for (int i = 0; i < 2; ++i)
        #pragma unroll
        for (int j = 0; j < 8; ++j) acc[i][j] = zero;

    #pragma unroll
    for (int kk = 0; kk < 2; ++kk) {
        const int kb = (kk << 6) + (lq << 4);
        short8 afr[2];
        #pragma unroll
        for (int rt = 0; rt < 2; ++rt) {
            const int r = (wid << 5) + (rt << 4) + l15;
            afr[rt] = *(const short8*)(As + (r << 7) + (kb ^ ((r & 7) << 4)));
        }
        #pragma unroll
        for (int ct = 0; ct < 8; ++ct) {
            const int n = (ct << 4) + l15;
            const short8 bfr = *(const short8*)(wxt + (n << 7) + (kb ^ ((n & 7) << 4)));
            acc[0][ct] = __builtin_amdgcn_mfma_f32_16x16x32_bf16(bfr, afr[0], acc[0][ct], 0, 0, 0);
            acc[1][ct] = __builtin_amdgcn_mfma_f32_16x16x32_bf16(bfr, afr[1], acc[1][ct], 0, 0, 0);
        }
    }

    #pragma unroll
    for (int rt = 0; rt < 2; ++rt) {
        const int grow = m0 + (wid << 5) + (rt << 4) + l15;   // node
        if (grow < NNODES) {
            #pragma unroll
            for (int ct = 0; ct < 8; ++ct) {
                uint2 pk;
                pk.x = f2bf(acc[rt][ct][0]) | (f2bf(acc[rt][ct][1]) << 16);
                pk.y = f2bf(acc[rt][ct][2]) | (f2bf(acc[rt][ct][3]) << 16);
                *(uint2*)(out + (size_t)grow * 128 + (ct << 4) + (lq << 2)) = pk;
            }
        }
    }
}

// ---------------- per-layer GEMM: xw(bf16) = BNrelu(in_bf16) @ Wg[l] ----------------
// Grid 512 = 2 blocks/CU exactly resident. B staged once per block via
// global_load_lds; grid-stride over A tiles with REGISTER software pipeline:
// next tile's raw A loads issued before the MFMA so HBM latency hides under it.

__global__ __launch_bounds__(256) void k_gemm(const unsigned short* __restrict__ in,
                                              const char* __restrict__ wt,
                                              unsigned short* __restrict__ out,
                                              const float* __restrict__ bnsc,
                                              const float* __restrict__ bnsh,
                                              int apply_bn) {
    __shared__ char As[32768];   // A tile, swizzled 256B rows
    __shared__ char Bs[32768];   // W^T image copy

    const int tid = threadIdx.x;
    const int lane = tid & 63;
    const int wid = tid >> 6;
    const int l15 = lane & 15;
    const int lq = lane >> 4;

    { // stage B once: 32 chunks of 1KB, wave-linear global_load_lds
        #pragma unroll
        for (int i = 0; i < 8; ++i) {
            const int chunk = ((i << 2) + wid) << 10;   // (i*4 + wave) * 1024
            __builtin_amdgcn_global_load_lds(
                (const __attribute__((address_space(1))) unsigned int*)(wt + chunk + (lane << 4)),
                (__attribute__((address_space(3))) unsigned int*)(Bs + chunk),
                16, 0, 0);
        }
    }
    // BN coeffs (tile-invariant), 8 channels per thread
    const int c0 = (tid & 15) << 3;
    const int r0 = tid >> 4;   // 0..15
    float scv[8], shv[8];
    #pragma unroll
    for (int j = 0; j < 8; ++j) {
        scv[j] = apply_bn ? bnsc[c0 + j] : 1.f;
        shv[j] = apply_bn ? bnsh[c0 + j] : 0.f;
    }

    uint4 areg[8];
    { // prologue: load first tile's raw A
        const int m0 = blockIdx.x << 7;
        #pragma unroll
        for (int it = 0; it < 8; ++it) {
            const int grow = m0 + r0 + (it << 4);
            uint4 p = {0u, 0u, 0u, 0u};
            if (blockIdx.x < NTILES && grow < NNODES)
                p = *(const uint4*)(in + (size_t)grow * 128 + c0);
            areg[it] = p;
        }
    }

    for (int tile = blockIdx.x; tile < NTILES; tile += gridDim.x) {
        { // transform current regs + swizzled ds_write
            #pragma unroll
            for (int it = 0; it < 8; ++it) {
                const int r = r0 + (it << 4);
                uint4 raw = areg[it];
                uint4 p;
                if (apply_bn) {
                    float e0 = fmaxf(fmaf(bf2f(raw.x & 0xffffu), scv[0], shv[0]), 0.f);
                    float e1 = fmaxf(fmaf(bf2f(raw.x >> 16),     scv[1], shv[1]), 0.f);
                    float e2 = fmaxf(fmaf(bf2f(raw.y & 0xffffu), scv[2], shv[2]), 0.f);
                    float e3 = fmaxf(fmaf(bf2f(raw.y >> 16),     scv[3], shv[3]), 0.f);
                    float e4 = fmaxf(fmaf(bf2f(raw.z & 0xffffu), scv[4], shv[4]), 0.f);
                    float e5 = fmaxf(fmaf(bf2f(raw.z >> 16),     scv[5], shv[5]), 0.f);
                    float e6 = fmaxf(fmaf(bf2f(raw.w & 0xffffu), scv[6], shv[6]), 0.f);
                    float e7 = fmaxf(fmaf(bf2f(raw.w >> 16),     scv[7], shv[7]), 0.f);
                    p.x = f2bf(e0) | (f2bf(e1) << 16);
                    p.y = f2bf(e2) | (f2bf(e3) << 16);
                    p.z = f2bf(e4) | (f2bf(e5) << 16);
                    p.w = f2bf(e6) | (f2bf(e7) << 16);
                } else {
                    p = raw;   // already bf16
                }
                *(uint4*)(As + (r << 8) + ((c0 << 1) ^ ((r & 7) << 4))) = p;
            }
        }
        __syncthreads();   // first iter also drains B DMA (vmcnt)

        { // issue next tile's raw A loads (in flight during MFMA + C-write)
            const int tn = tile + gridDim.x;
            const int m0n = tn << 7;
            #pragma unroll
            for (int it = 0; it < 8; ++it) {
                const int grow = m0n + r0 + (it << 4);
                uint4 p = {0u, 0u, 0u, 0u};
                if (tn < NTILES && grow < NNODES)
                    p = *(const uint4*)(in + (size_t)grow * 128 + c0);
                areg[it] = p;
            }
        }

        const f32x4 zero = {0.f, 0.f, 0.f, 0.f};
        f32x4 acc[2][8];
        #pragma unroll
        for (int i = 0; i < 2; ++i)
            #pragma unroll
            for (int j = 0; j < 8; ++j) acc[i][j] = zero;

        #pragma unroll
        for (int kk = 0; kk < 4; ++kk) {
            const int kb = (kk << 6) + (lq << 4);
            short8 afr[2];
            #pragma unroll
            for (int rt = 0; rt < 2; ++rt) {
                const int r = (wid << 5) + (rt << 4) + l15;
                afr[rt] = *(const short8*)(As + (r << 8) + (kb ^ ((r & 7) << 4)));
            }
            #pragma unroll
            for (int ct = 0; ct < 8; ++ct) {
                const int n = (ct << 4) + l15;
                const short8 bfr = *(const short8*)(Bs + (n << 8) + (kb ^ ((n & 7) << 4)));
                // swapped operands: D[channel][node]
                acc[0][ct] = __builtin_amdgcn_mfma_f32_16x16x32_bf16(bfr, afr[0], acc[0][ct], 0, 0, 0);
                acc[1][ct] = __builtin_amdgcn_mfma_f32_16x16x32_bf16(bfr, afr[1], acc[1][ct], 0, 0, 0);
            }
        }

        const int m0 = tile << 7;
        #pragma unroll
        for (int rt = 0; rt < 2; ++rt) {
            const int grow = m0 + (wid << 5) + (rt << 4) + l15;   // node
            if (grow < NNODES) {
                #pragma unroll
                for (int ct = 0; ct < 8; ++ct) {
                    uint2 pk;
                    pk.x = f2bf(acc[rt][ct][0]) | (f2bf(acc[rt][ct][1]) << 16);
                    pk.y = f2bf(acc[rt][ct][2]) | (f2bf(acc[rt][ct][3]) << 16);
                    *(uint2*)(out + (size_t)grow * 128 + (ct << 4) + (lq << 2)) = pk;
                }
            }
        }
        __syncthreads();   // protect As before next tile's stage
    }
}

// ------- aggregation: agg_l = bg + BNrelu(prev) + D^-1/2 A D^-1/2 xw ; fused BN stats -------
// R6 structure + batch-8 edge loop: 8 metadata + 8 uint4 gathers in flight per
// slot (32/wave during gather) to raise MLP per Little's law. Grid 2048.

__global__ __launch_bounds__(256) void k_agg(const unsigned short* __restrict__ prev,
                                             const unsigned short* __restrict__ xw,
                                             const float* __restrict__ dinv,
                                             const int* __restrict__ roff,
                                             const int2* __restrict__ cedge,
                                             const float* __restrict__ bg,
                                             const float* __restrict__ bnsc,
                                             const float* __restrict__ bnsh,
                                             int apply_bn,
                                             unsigned short* __restrict__ outb,
                                             float* __restrict__ statsOut) {
    const int lane = threadIdx.x & 63;
    const int wv   = threadIdx.x >> 6;       // wave 0..3
    const int g16  = lane >> 4;              // node slot within wave 0..3
    const int l16  = lane & 15;
    const int c8   = l16 << 3;               // channel base (8 channels per lane)

    float sc[8], sh[8], bgv[8];
    #pragma unroll
    for (int j = 0; j < 8; ++j) {
        sc[j] = apply_bn ? bnsc[c8 + j] : 1.f;
        sh[j] = apply_bn ? bnsh[c8 + j] : 0.f;
        bgv[j] = bg[c8 + j];
    }
    float s_[8], q_[8];
    #pragma unroll
    for (int j = 0; j < 8; ++j) { s_[j] = 0.f; q_[j] = 0.f; }

    const int stride = gridDim.x * 16;
    for (int v = blockIdx.x * 16 + wv * 4 + g16; v < NNODES; v += stride) {
        const int rof0 = roff[v];
        const int rof1 = roff[v + 1];
        const float dv = dinv[v];
        const uint4 resu  = *(const uint4*)(prev + (size_t)v * 128 + c8);
        const uint4 selfu = *(const uint4*)(xw + (size_t)v * 128 + c8);
        float a[8];
        {
            float r[8];
            r[0] = bf2f(resu.x & 0xffffu); r[1] = bf2f(resu.x >> 16);
            r[2] = bf2f(resu.y & 0xffffu); r[3] = bf2f(resu.y >> 16);
            r[4] = bf2f(resu.z & 0xffffu); r[5] = bf2f(resu.z >> 16);
            r[6] = bf2f(resu.w & 0xffffu); r[7] = bf2f(resu.w >> 16);
            if (apply_bn) {
                #pragma unroll
                for (int j = 0; j < 8; ++j)
                    a[j] = bgv[j] + fmaxf(fmaf(r[j], sc[j], sh[j]), 0.f);
            } else {
                #pragma unroll
                for (int j = 0; j < 8; ++j) a[j] = bgv[j] + r[j];
            }
            acc8(a, dv * dv, selfu);
        }
        int e = rof0;
        while (e < rof1) {
            const int rem = rof1 - e;
            int2 d[8];
            d[0] = cedge[e];
            #pragma unroll
            for (int i = 1; i < 8; ++i) d[i] = cedge[rem > i ? e + i : e];
            uint4 g[8];
            #pragma unroll
            for (int i = 0; i < 8; ++i)
                g[i] = *(const uint4*)(xw + (size_t)d[i].x * 128 + c8);
            acc8(a, __int_as_float(d[0].y), g[0]);
            #pragma unroll
            for (int i = 1; i < 8; ++i) {
                const float wgt = rem > i ? __int_as_float(d[i].y) : 0.f;
                acc8(a, wgt, g[i]);
            }
            e += 8;
        }
        uint4 o;
        o.x = f2bf(a[0]) | (f2bf(a[1]) << 16);
        o.y = f2bf(a[2]) | (f2bf(a[3]) << 16);
        o.z = f2bf(a[4]) | (f2bf(a[5]) << 16);
        o.w = f2bf(a[6]) | (f2bf(a[7]) << 16);
        *(uint4*)(outb + (size_t)v * 128 + c8) = o;
        #pragma unroll
        for (int j = 0; j < 8; ++j) {
            s_[j] += a[j];
            q_[j] = fmaf(a[j], a[j], q_[j]);
        }
    }

    // combine the 4 node-slots (channels depend on l16 only)
    #pragma unroll
    for (int j = 0; j < 8; ++j) {
        s_[j] += __shfl_xor(s_[j], 16); s_[j] += __shfl_xor(s_[j], 32);
        q_[j] += __shfl_xor(q_[j], 16); q_[j] += __shfl_xor(q_[j], 32);
    }
    __shared__ float red[512];
    if (g16 == 0) {
        #pragma unroll
        for (int j = 0; j < 8; ++j) red[wv * 128 + c8 + j] = s_[j];
    }
    __syncthreads();
    if (threadIdx.x < 128) {
        const int ch = threadIdx.x;
        atomicAdd(&statsOut[ch], red[ch] + red[128 + ch] + red[256 + ch] + red[384 + ch]);
    }
    __syncthreads();
    if (g16 == 0) {
        #pragma unroll
        for (int j = 0; j < 8; ++j) red[wv * 128 + c8 + j] = q_[j];
    }
    __syncthreads();
    if (threadIdx.x < 128) {
        const int ch = threadIdx.x;
        atomicAdd(&statsOut[128 + ch], red[ch] + red[128 + ch] + red[256 + ch] + red[384 + ch]);
    }
}

// ---------------- pooling (sorted batch ranges) + readout MLP ----------------

__global__ __launch_bounds__(128) void k_pool(const unsigned short* __restrict__ agg,
                                              const float* __restrict__ bnsc,
                                              const float* __restrict__ bnsh,
                                              const int* __restrict__ gstart,
                                              const float* __restrict__ W1, const float* __restrict__ b1,
                                              const float* __restrict__ W2, const float* __restrict__ b2,
                                              const float* __restrict__ W3, const float* __restrict__ b3,
                                              float* __restrict__ out) {
    __shared__ float mol[128];
    __shared__ float h1s[128];
    const int g = blockIdx.x;
    const int c = threadIdx.x;
    const float sc = bnsc[c], sh = bnsh[c];
    const int v0 = gstart[g], v1 = gstart[g + 1];
    float acc = 0.f;
    for (int v = v0; v < v1; ++v)
        acc += fmaf(bf2f(agg[(size_t)v * 128 + c]), sc, sh);  // last layer: BN, no relu
    mol[c] = acc;
    __syncthreads();
    float a1 = b1[c];
    #pragma unroll 8
    for (int k = 0; k < 128; ++k) a1 = fmaf(mol[k], W1[k * 128 + c], a1);
    h1s[c] = fmaxf(a1, 0.f);
    __syncthreads();
    if (c < 64) {
        float a2 = b2[c];
        #pragma unroll 8
        for (int k = 0; k < 128; ++k) a2 = fmaf(h1s[k], W2[k * 64 + c], a2);
        float p = fmaxf(a2, 0.f) * W3[c];
        #pragma unroll
        for (int o = 32; o > 0; o >>= 1) p += __shfl_down(p, o);
        if (c == 0) out[g] = p + b3[0];
    }
}

// ---------------- launch ----------------

extern "C" void kernel_launch(void* const* d_in, const int* in_sizes, int n_in,
                              void* d_out, int out_size, void* d_ws, size_t ws_size,
                              hipStream_t stream) {
    (void)in_sizes; (void)n_in; (void)out_size; (void)ws_size;
    const float* x     = (const float*)d_in[0];
    const int*   ei    = (const int*)d_in[1];
    const int*   batch = (const int*)d_in[2];
    const float* Wx    = (const float*)d_in[3];
    const float* bx    = (const float*)d_in[4];
    const float* Wg    = (const float*)d_in[5];
    const float* bg    = (const float*)d_in[6];
    const float* gamma = (const float*)d_in[7];
    const float* beta  = (const float*)d_in[8];
    const float* W1    = (const float*)d_in[9];
    const float* b1    = (const float*)d_in[10];
    const float* W2    = (const float*)d_in[11];
    const float* b2    = (const float*)d_in[12];
    const float* W3    = (const float*)d_in[13];
    const float* b3    = (const float*)d_in[14];
    float* out = (float*)d_out;

    char* ws = (char*)d_ws;
    size_t off = 0;
    auto alloc = [&](size_t bytes) -> char* {
        char* p = ws + off;
        off += (bytes + 255) & ~(size_t)255;
        return p;
    };
    unsigned short* aggA   = (unsigned short*)alloc((size_t)NNODES * 128 * 2);
    unsigned short* aggB   = (unsigned short*)alloc((size_t)NNODES * 128 * 2);
    unsigned short* xw     = (unsigned short*)alloc((size_t)NNODES * 128 * 2);
    float*          dinv   = (float*)alloc((size_t)NNODES * 4);
    int*            cnt    = (int*)alloc((size_t)NNODES * 4);
    int*            cursor = (int*)alloc((size_t)NNODES * 4);
    int*            roff   = (int*)alloc((size_t)(NNODES + 1) * 4);
    int2*           cedge  = (int2*)alloc((size_t)(NEDGES + 8) * 8);
    char*           wt     = alloc((size_t)NLAYERS * 32768);
    char*           wxt    = alloc((size_t)16384);
    float*          stats  = (float*)alloc((size_t)NLAYERS * 256 * 4);
    float*          bnsc   = (float*)alloc((size_t)NLAYERS * 128 * 4);
    float*          bnsh   = (float*)alloc((size_t)NLAYERS * 128 * 4);
    int*            gstart = (int*)alloc((size_t)(NGRAPHS + 1) * 4);
    int*            bsum   = (int*)alloc((size_t)1024 * 4);

    const int NB = (NNODES + 255) / 256;   // 782
    const int EB = (NEDGES + 255) / 256;   // 1563
    const int WB = (NLAYERS * 16384 + 8192 + 255) / 256;

    k_init<<<NB, 256, 0, stream>>>(cnt, cursor, stats);
    k_count<<<EB, 256, 0, stream>>>(ei, cnt);
    k_scan1<<<NB, 256, 0, stream>>>(cnt, roff, bsum, batch, gstart);
    k_scan2<<<1, 1024, 0, stream>>>(bsum, NB);
    k_scan3<<<NB, 256, 0, stream>>>(roff, bsum, cnt, dinv);
    k_fill<<<EB, 256, 0, stream>>>(ei, dinv, roff, cursor, cedge);
    k_wtrans<<<WB, 256, 0, stream>>>(Wg, Wx, bx, wt, wxt);
    k_inproj<<<NTILES, 256, 0, stream>>>(x, wxt, aggA);

    unsigned short* cur = aggA;
    unsigned short* nxt = aggB;
    for (int l = 0; l < NLAYERS; ++l) {
        const float* psc = (l > 0) ? (bnsc + (l - 1) * 128) : (const float*)nullptr;
        const float* psh = (l > 0) ? (bnsh + (l - 1) * 128) : (const float*)nullptr;
        k_gemm<<<512, 256, 0, stream>>>(cur, wt + (size_t)l * 32768, xw, psc, psh, l > 0);
        k_agg<<<2048, 256, 0, stream>>>(cur, xw, dinv, roff, cedge, bg + l * 128,
                                        psc, psh, l > 0, nxt, stats + l * 256);
        k_bnfin<<<1, 128, 0, stream>>>(stats + l * 256, gamma + l * 128, beta + l * 128,
                                       bnsc + l * 128, bnsh + l * 128);
        unsigned short* t = cur; cur = nxt; nxt = t;
    }

    k_pool<<<NGRAPHS, 128, 0, stream>>>(cur, bnsc + 4 * 128, bnsh + 4 * 128, gstart,
                                        W1, b1, W2, b2, W3, b3, out);
}

// Round 13
// 723.138 us; speedup vs baseline: 1.3265x; 1.0274x over previous
//
#include <hip/hip_runtime.h>
#include <stdint.h>

#define NNODES  200000
#define NEDGES  400000
#define NGRAPHS 4000
#define NLAYERS 5
#define BN_EPS  1e-5f
#define INV_N   (1.0f / (float)NNODES)
#define NTILES  ((NNODES + 127) / 128)   // 1563

typedef __attribute__((ext_vector_type(8))) short short8;
typedef __attribute__((ext_vector_type(4))) float f32x4;

__device__ __forceinline__ unsigned int f2bf(float f) {
    unsigned int u = __float_as_uint(f);
    return (u + 0x7fffu + ((u >> 16) & 1u)) >> 16;
}
__device__ __forceinline__ float bf2f(unsigned int b) {
    return __uint_as_float(b << 16);
}

__device__ __forceinline__ void acc8(float (&a)[8], float wgt, const uint4& g) {
    a[0] = fmaf(wgt, bf2f(g.x & 0xffffu), a[0]);
    a[1] = fmaf(wgt, bf2f(g.x >> 16),     a[1]);
    a[2] = fmaf(wgt, bf2f(g.y & 0xffffu), a[2]);
    a[3] = fmaf(wgt, bf2f(g.y >> 16),     a[3]);
    a[4] = fmaf(wgt, bf2f(g.z & 0xffffu), a[4]);
    a[5] = fmaf(wgt, bf2f(g.z >> 16),     a[5]);
    a[6] = fmaf(wgt, bf2f(g.w & 0xffffu), a[6]);
    a[7] = fmaf(wgt, bf2f(g.w >> 16),     a[7]);
}

// ---------------- graph prep ----------------

__global__ void k_init(int* __restrict__ cnt, int* __restrict__ cursor,
                       float* __restrict__ stats) {
    int i = blockIdx.x * 256 + threadIdx.x;
    if (i < NNODES) { cnt[i] = 0; cursor[i] = 0; }
    if (i < NLAYERS * 256) stats[i] = 0.f;
}

__global__ void k_count(const int* __restrict__ ei, int* __restrict__ cnt) {
    int e = blockIdx.x * 256 + threadIdx.x;
    if (e < NEDGES) atomicAdd(&cnt[ei[NEDGES + e]], 1);
}

// block-scan of cnt (real edges only); also graph ranges from sorted batch
__global__ __launch_bounds__(256) void k_scan1(const int* __restrict__ cnt,
                                               int* __restrict__ roff, int* __restrict__ bsum,
                                               const int* __restrict__ batch,
                                               int* __restrict__ gstart) {
    __shared__ int s[256];
    int t = threadIdx.x;
    int v = blockIdx.x * 256 + t;
    int val = (v < NNODES) ? cnt[v] : 0;
    s[t] = val; __syncthreads();
    int sum = val;
    for (int o = 1; o < 256; o <<= 1) {
        int tmp = (t >= o) ? s[t - o] : 0;
        __syncthreads();
        sum += tmp; s[t] = sum;
        __syncthreads();
    }
    if (v < NNODES) roff[v] = sum - val;       // exclusive within block
    if (t == 255) bsum[blockIdx.x] = s[255];

    if (v < NNODES) {   // graph ranges (merged k_ranges)
        int b = batch[v];
        if (v == 0) {
            for (int g = 0; g <= b; ++g) gstart[g] = 0;
        } else {
            int pb = batch[v - 1];
            for (int g = pb + 1; g <= b; ++g) gstart[g] = v;
        }
        if (v == NNODES - 1) {
            for (int g = b + 1; g <= NGRAPHS; ++g) gstart[g] = NNODES;
        }
    }
}

__global__ __launch_bounds__(1024) void k_scan2(int* __restrict__ bsum, int nb) {
    __shared__ int s[1024];
    int t = threadIdx.x;
    int val = (t < nb) ? bsum[t] : 0;
    s[t] = val; __syncthreads();
    int sum = val;
    for (int o = 1; o < 1024; o <<= 1) {
        int tmp = (t >= o) ? s[t - o] : 0;
        __syncthreads();
        sum += tmp; s[t] = sum;
        __syncthreads();
    }
    if (t < nb) bsum[t] = sum - val;           // exclusive block offsets
}

// finalize roff; compute dinv
__global__ void k_scan3(int* __restrict__ roff, const int* __restrict__ bsum,
                        const int* __restrict__ cnt, float* __restrict__ dinv) {
    int v = blockIdx.x * 256 + threadIdx.x;
    if (v < NNODES) {
        roff[v] += bsum[blockIdx.x];
        dinv[v] = rsqrtf((float)cnt[v] + 1.0f);
    }
    if (v == 0) roff[NNODES] = NEDGES;
}

__global__ void k_fill(const int* __restrict__ ei, const float* __restrict__ dinv,
                       const int* __restrict__ roff, int* __restrict__ cursor,
                       int2* __restrict__ cedge) {
    int e = blockIdx.x * 256 + threadIdx.x;
    if (e >= NEDGES) return;
    int s = ei[e], d = ei[NEDGES + e];
    int pos = atomicAdd(&cursor[d], 1);
    int idx = roff[d] + pos;
    int2 ed; ed.x = s; ed.y = __float_as_int(dinv[s] * dinv[d]);
    cedge[idx] = ed;
}

// transpose + bf16-convert + swizzle layer weights WT[n][k]=W[k][n] (256B rows),
// and Wx -> WxT[n][k0..63] zero-padded (128B rows), with bias folded at k=40.
__global__ void k_wtrans(const float* __restrict__ Wg, const float* __restrict__ Wx,
                         const float* __restrict__ bx,
                         char* __restrict__ wt, char* __restrict__ wxt) {
    int idx = blockIdx.x * 256 + threadIdx.x;
    if (idx < NLAYERS * 16384) {
        int l = idx >> 14;
        int rem = idx & 16383;
        int n = rem >> 7;
        int k = rem & 127;
        float v = Wg[l * 16384 + k * 128 + n];
        char* img = wt + l * 32768;
        *(unsigned short*)(img + (n << 8) + ((k << 1) ^ ((n & 7) << 4))) = (unsigned short)f2bf(v);
    } else if (idx < NLAYERS * 16384 + 8192) {
        int j = idx - NLAYERS * 16384;
        int n = j >> 6;
        int k = j & 63;
        float v = (k < 40) ? Wx[k * 128 + n] : (k == 40 ? bx[n] : 0.f);
        *(unsigned short*)(wxt + (n << 7) + ((k << 1) ^ ((n & 7) << 4))) = (unsigned short)f2bf(v);
    }
}

// BN finalize: per-channel scale/shift from raw stats (tiny kernel, 1 block)
__global__ void k_bnfin(const float* __restrict__ stats, const float* __restrict__ gamma,
                        const float* __restrict__ beta, float* __restrict__ sc,
                        float* __restrict__ sh) {
    int c = threadIdx.x;
    float mean = stats[c] * INV_N;
    float var = stats[128 + c] * INV_N - mean * mean;
    float s = gamma[c] * rsqrtf(var + BN_EPS);
    sc[c] = s;
    sh[c] = fmaf(-mean, s, beta[c]);
}

// ---------------- input projection (MFMA): h0 = bf16(x @ Wx + bx) ----------------

__global__ __launch_bounds__(256) void k_inproj(const float* __restrict__ x,
                                                const char* __restrict__ wxt,
                                                unsigned short* __restrict__ out) {
    __shared__ char As[16384];   // 128 rows * 128 B
    const int tid = threadIdx.x;
    const int m0 = blockIdx.x << 7;

    { // stage A: 16 threads per row cover k 0..63 (4 each); k=40 -> 1.0
        const int kq = (tid & 15) << 2;   // 0,4,...,60
        const int r0 = tid >> 4;          // 0..15
        #pragma unroll
        for (int it = 0; it < 8; ++it) {
            const int r = r0 + (it << 4);
            const int grow = m0 + r;
            float x0 = 0.f, x1 = 0.f, x2 = 0.f, x3 = 0.f;
            if (grow < NNODES) {
                if (kq < 40) {
                    const float4 v = *(const float4*)(x + (size_t)grow * 40 + kq);
                    x0 = v.x; x1 = v.y; x2 = v.z; x3 = v.w;
                } else if (kq == 40) {
                    x0 = 1.0f;   // homogeneous coordinate -> bias via MFMA
                }
            }
            uint2 p;
            p.x = f2bf(x0) | (f2bf(x1) << 16);
            p.y = f2bf(x2) | (f2bf(x3) << 16);
            *(uint2*)(As + (r << 7) + ((kq << 1) ^ ((r & 7) << 4))) = p;
        }
    }
    __syncthreads();

    const int lane = tid & 63;
    const int wid = tid >> 6;
    const int l15 = lane & 15;
    const int lq = lane >> 4;

    const f32x4 zero = {0.f, 0.f, 0.f, 0.f};
    f32x4 acc[2][8];
    #pragma unroll
    for (int i = 0; i < 2; ++i)
        #pragma unroll
        for (int j = 0; j < 8; ++j) acc[i][j] = zero;

    #pragma unroll
    for (int kk = 0; kk < 2; ++kk) {
        const int kb = (kk << 6) + (lq << 4);
        short8 afr[2];
        #pragma unroll
        for (int rt = 0; rt < 2; ++rt) {
            const int r = (wid << 5) + (rt << 4) + l15;
            afr[rt] = *(const short8*)(As + (r << 7) + (kb ^ ((r & 7) << 4)));
        }
        #pragma unroll
        for (int ct = 0; ct < 8; ++ct) {
            const int n = (ct << 4) + l15;
            const short8 bfr = *(const short8*)(wxt + (n << 7) + (kb ^ ((n & 7) << 4)));
            acc[0][ct] = __builtin_amdgcn_mfma_f32_16x16x32_bf16(bfr, afr[0], acc[0][ct], 0, 0, 0);
            acc[1][ct] = __builtin_amdgcn_mfma_f32_16x16x32_bf16(bfr, afr[1], acc[1][ct], 0, 0, 0);
        }
    }

    #pragma unroll
    for (int rt = 0; rt < 2; ++rt) {
        const int grow = m0 + (wid << 5) + (rt << 4) + l15;   // node
        if (grow < NNODES) {
            #pragma unroll
            for (int ct = 0; ct < 8; ++ct) {
                uint2 pk;
                pk.x = f2bf(acc[rt][ct][0]) | (f2bf(acc[rt][ct][1]) << 16);
                pk.y = f2bf(acc[rt][ct][2]) | (f2bf(acc[rt][ct][3]) << 16);
                *(uint2*)(out + (size_t)grow * 128 + (ct << 4) + (lq << 2)) = pk;
            }
        }
    }
}

// ---------------- per-layer GEMM: xw(bf16) = BNrelu(in_bf16) @ Wg[l] ----------------
// Grid 512 = 2 blocks/CU (LDS-limited). B staged once per block via global_load_lds;
// grid-stride over A tiles; register pipeline on A; C-write staged through LDS
// (swizzled) then stored LINEARLY (tile bytes contiguous) -> 1KB/instr coalesced.
// Tail tile over-stores into padded slack of xw (32KB), so no store guards.

__global__ __launch_bounds__(256) void k_gemm(const unsigned short* __restrict__ in,
                                              const char* __restrict__ wt,
                                              unsigned short* __restrict__ out,
                                              const float* __restrict__ bnsc,
                                              const float* __restrict__ bnsh,
                                              int apply_bn) {
    __shared__ char As[32768];   // A tile / C staging, swizzled 256B rows
    __shared__ char Bs[32768];   // W^T image copy

    const int tid = threadIdx.x;
    const int lane = tid & 63;
    const int wid = tid >> 6;
    const int l15 = lane & 15;
    const int lq = lane >> 4;

    { // stage B once: 32 chunks of 1KB, wave-linear global_load_lds
        #pragma unroll
        for (int i = 0; i < 8; ++i) {
            const int chunk = ((i << 2) + wid) << 10;   // (i*4 + wave) * 1024
            __builtin_amdgcn_global_load_lds(
                (const __attribute__((address_space(1))) unsigned int*)(wt + chunk + (lane << 4)),
                (__attribute__((address_space(3))) unsigned int*)(Bs + chunk),
                16, 0, 0);
        }
    }
    // BN coeffs (tile-invariant), 8 channels per thread
    const int c0 = (tid & 15) << 3;
    const int r0 = tid >> 4;   // 0..15
    float scv[8], shv[8];
    #pragma unroll
    for (int j = 0; j < 8; ++j) {
        scv[j] = apply_bn ? bnsc[c0 + j] : 1.f;
        shv[j] = apply_bn ? bnsh[c0 + j] : 0.f;
    }

    uint4 areg[8];
    { // prologue: load first tile's raw A
        const int m0 = blockIdx.x << 7;
        #pragma unroll
        for (int it = 0; it < 8; ++it) {
            const int grow = m0 + r0 + (it << 4);
            uint4 p = {0u, 0u, 0u, 0u};
            if (grow < NNODES)
                p = *(const uint4*)(in + (size_t)grow * 128 + c0);
            areg[it] = p;
        }
    }

    for (int tile = blockIdx.x; tile < NTILES; tile += gridDim.x) {
        { // transform current regs + swizzled ds_write
            #pragma unroll
            for (int it = 0; it < 8; ++it) {
                const int r = r0 + (it << 4);
                uint4 raw = areg[it];
                uint4 p;
                if (apply_bn) {
                    float e0 = fmaxf(fmaf(bf2f(raw.x & 0xffffu), scv[0], shv[0]), 0.f);
                    float e1 = fmaxf(fmaf(bf2f(raw.x >> 16),     scv[1], shv[1]), 0.f);
                    float e2 = fmaxf(fmaf(bf2f(raw.y & 0xffffu), scv[2], shv[2]), 0.f);
                    float e3 = fmaxf(fmaf(bf2f(raw.y >> 16),     scv[3], shv[3]), 0.f);
                    float e4 = fmaxf(fmaf(bf2f(raw.z & 0xffffu), scv[4], shv[4]), 0.f);
                    float e5 = fmaxf(fmaf(bf2f(raw.z >> 16),     scv[5], shv[5]), 0.f);
                    float e6 = fmaxf(fmaf(bf2f(raw.w & 0xffffu), scv[6], shv[6]), 0.f);
                    float e7 = fmaxf(fmaf(bf2f(raw.w >> 16),     scv[7], shv[7]), 0.f);
                    p.x = f2bf(e0) | (f2bf(e1) << 16);
                    p.y = f2bf(e2) | (f2bf(e3) << 16);
                    p.z = f2bf(e4) | (f2bf(e5) << 16);
                    p.w = f2bf(e6) | (f2bf(e7) << 16);
                } else {
                    p = raw;   // already bf16
                }
                *(uint4*)(As + (r << 8) + ((c0 << 1) ^ ((r & 7) << 4))) = p;
            }
        }
        __syncthreads();   // first iter also drains B DMA (vmcnt)

        { // issue next tile's raw A loads (in flight during MFMA + C-write)
            const int tn = tile + gridDim.x;
            const int m0n = tn << 7;
            #pragma unroll
            for (int it = 0; it < 8; ++it) {
                const int grow = m0n + r0 + (it << 4);
                uint4 p = {0u, 0u, 0u, 0u};
                if (tn < NTILES && grow < NNODES)
                    p = *(const uint4*)(in + (size_t)grow * 128 + c0);
                areg[it] = p;
            }
        }

        const f32x4 zero = {0.f, 0.f, 0.f, 0.f};
        f32x4 acc[2][8];
        #pragma unroll
        for (int i = 0; i < 2; ++i)
            #pragma unroll
            for (int j = 0; j < 8; ++j) acc[i][j] = zero;

        #pragma unroll
        for (int kk = 0; kk < 4; ++kk) {
            const int kb = (kk << 6) + (lq << 4);
            short8 afr[2];
            #pragma unroll
            for (int rt = 0; rt < 2; ++rt) {
                const int r = (wid << 5) + (rt << 4) + l15;
                afr[rt] = *(const short8*)(As + (r << 8) + (kb ^ ((r & 7) << 4)));
            }
            #pragma unroll
            for (int ct = 0; ct < 8; ++ct) {
                const int n = (ct << 4) + l15;
                const short8 bfr = *(const short8*)(Bs + (n << 8) + (kb ^ ((n & 7) << 4)));
                // swapped operands: D[channel][node]
                acc[0][ct] = __builtin_amdgcn_mfma_f32_16x16x32_bf16(bfr, afr[0], acc[0][ct], 0, 0, 0);
                acc[1][ct] = __builtin_amdgcn_mfma_f32_16x16x32_bf16(bfr, afr[1], acc[1][ct], 0, 0, 0);
            }
        }
        __syncthreads();   // all waves done reading As -> reuse as C staging

        { // stage C into As (swizzled uint2 writes)
            #pragma unroll
            for (int rt = 0; rt < 2; ++rt) {
                const int r = (wid << 5) + (rt << 4) + l15;
                #pragma unroll
                for (int ct = 0; ct < 8; ++ct) {
                    uint2 pk;
                    pk.x = f2bf(acc[rt][ct][0]) | (f2bf(acc[rt][ct][1]) << 16);
                    pk.y = f2bf(acc[rt][ct][2]) | (f2bf(acc[rt][ct][3]) << 16);
                    const int bo = (ct << 5) + (lq << 3);   // channel bytes within row
                    *(uint2*)(As + (r << 8) + (bo ^ ((r & 7) << 4))) = pk;
                }
            }
        }
        __syncthreads();

        { // linear coalesced store: tile occupies contiguous 32KB of out
            char* gout = (char*)out + ((size_t)tile << 15);
            #pragma unroll
            for (int k = 0; k < 8; ++k) {
                const int off = (tid << 4) + (k << 12);
                const int r = off >> 8;
                const int bo = off & 255;
                const uint4 val = *(const uint4*)(As + (r << 8) + (bo ^ ((r & 7) << 4)));
                *(uint4*)(gout + off) = val;   // tail tile lands in xw slack
            }
        }
        __syncthreads();   // protect As before next tile's stage
    }
}

// ------- aggregation: agg_l = bg + BNrelu(prev) + D^-1/2 A D^-1/2 xw ; fused BN stats -------
// R11 structure (batch-4, VGPR~52) + cross-node prefetch (+11 VGPR, stays <=64):
// next node's roff/dinv/resu/selfu issued before the current edge chain.

__global__ __launch_bounds__(256) void k_agg(const unsigned short* __restrict__ prev,
                                             const unsigned short* __restrict__ xw,
                                             const float* __restrict__ dinv,
                                             const int* __restrict__ roff,
                                             const int2* __restrict__ cedge,
                                             const float* __restrict__ bg,
                                             const float* __restrict__ bnsc,
                                             const float* __restrict__ bnsh,
                                             int apply_bn,
                                             unsigned short* __restrict__ outb,
                                             float* __restrict__ statsOut) {
    const int lane = threadIdx.x & 63;
    const int wv   = threadIdx.x >> 6;       // wave 0..3
    const int g16  = lane >> 4;              // node slot within wave 0..3
    const int l16  = lane & 15;
    const int c8   = l16 << 3;               // channel base (8 channels per lane)

    float sc[8], sh[8], bgv[8];
    #pragma unroll
    for (int j = 0; j < 8; ++j) {
        sc[j] = apply_bn ? bnsc[c8 + j] : 1.f;
        sh[j] = apply_bn ? bnsh[c8 + j] : 0.f;
        bgv[j] = bg[c8 + j];
    }
    float s_[8], q_[8];
    #pragma unroll
    for (int j = 0; j < 8; ++j) { s_[j] = 0.f; q_[j] = 0.f; }

    const int stride = gridDim.x * 16;
    int v = blockIdx.x * 16 + wv * 4 + g16;
    int rof0 = 0, rof1 = 0;
    float dv = 0.f;
    uint4 resu = {0u, 0u, 0u, 0u}, selfu = {0u, 0u, 0u, 0u};
    if (v < NNODES) {
        rof0 = roff[v]; rof1 = roff[v + 1];
        dv = dinv[v];
        resu  = *(const uint4*)(prev + (size_t)v * 128 + c8);
        selfu = *(const uint4*)(xw + (size_t)v * 128 + c8);
    }
    while (v < NNODES) {
        const int vn = v + stride;
        int nrof0 = 0, nrof1 = 0;
        float ndv = 0.f;
        uint4 nres = {0u, 0u, 0u, 0u}, nself = {0u, 0u, 0u, 0u};
        if (vn < NNODES) {   // prefetch next node before the edge chain
            nrof0 = roff[vn]; nrof1 = roff[vn + 1];
            ndv = dinv[vn];
            nres  = *(const uint4*)(prev + (size_t)vn * 128 + c8);
            nself = *(const uint4*)(xw + (size_t)vn * 128 + c8);
        }
        float a[8];
        {
            float r[8];
            r[0] = bf2f(resu.x & 0xffffu); r[1] = bf2f(resu.x >> 16);
            r[2] = bf2f(resu.y & 0xffffu); r[3] = bf2f(resu.y >> 16);
            r[4] = bf2f(resu.z & 0xffffu); r[5] = bf2f(resu.z >> 16);
            r[6] = bf2f(resu.w & 0xffffu); r[7] = bf2f(resu.w >> 16);
            if (apply_bn) {
                #pragma unroll
                for (int j = 0; j < 8; ++j)
                    a[j] = bgv[j] + fmaxf(fmaf(r[j], sc[j], sh[j]), 0.f);
            } else {
                #pragma unroll
                for (int j = 0; j < 8; ++j) a[j] = bgv[j] + r[j];
            }
            acc8(a, dv * dv, selfu);
        }
        int e = rof0;
        while (e < rof1) {
            const int rem = rof1 - e;
            const int2 d0 = cedge[e];
            const int2 d1 = cedge[rem > 1 ? e + 1 : e];
            const int2 d2 = cedge[rem > 2 ? e + 2 : e];
            const int2 d3 = cedge[rem > 3 ? e + 3 : e];
            const float w0 = __int_as_float(d0.y);
            const float w1 = rem > 1 ? __int_as_float(d1.y) : 0.f;
            const float w2 = rem > 2 ? __int_as_float(d2.y) : 0.f;
            const float w3 = rem > 3 ? __int_as_float(d3.y) : 0.f;
            const uint4 g0 = *(const uint4*)(xw + (size_t)d0.x * 128 + c8);
            const uint4 g1 = *(const uint4*)(xw + (size_t)d1.x * 128 + c8);
            const uint4 g2 = *(const uint4*)(xw + (size_t)d2.x * 128 + c8);
            const uint4 g3 = *(const uint4*)(xw + (size_t)d3.x * 128 + c8);
            acc8(a, w0, g0);
            acc8(a, w1, g1);
            acc8(a, w2, g2);
            acc8(a, w3, g3);
            e += 4;
        }
        uint4 o;
        o.x = f2bf(a[0]) | (f2bf(a[1]) << 16);
        o.y = f2bf(a[2]) | (f2bf(a[3]) << 16);
        o.z = f2bf(a[4]) | (f2bf(a[5]) << 16);
        o.w = f2bf(a[6]) | (f2bf(a[7]) << 16);
        *(uint4*)(outb + (size_t)v * 128 + c8) = o;
        #pragma unroll
        for (int j = 0; j < 8; ++j) {
            s_[j] += a[j];
            q_[j] = fmaf(a[j], a[j], q_[j]);
        }
        v = vn; rof0 = nrof0; rof1 = nrof1; dv = ndv; resu = nres; selfu = nself;
    }

    // combine the 4 node-slots (channels depend on l16 only)
    #pragma unroll
    for (int j = 0; j < 8; ++j) {
        s_[j] += __shfl_xor(s_[j], 16); s_[j] += __shfl_xor(s_[j], 32);
        q_[j] += __shfl_xor(q_[j], 16); q_[j] += __shfl_xor(q_[j], 32);
    }
    __shared__ float red[512];
    if (g16 == 0) {
        #pragma unroll
        for (int j = 0; j < 8; ++j) red[wv * 128 + c8 + j] = s_[j];
    }
    __syncthreads();
    if (threadIdx.x < 128) {
        const int ch = threadIdx.x;
        atomicAdd(&statsOut[ch], red[ch] + red[128 + ch] + red[256 + ch] + red[384 + ch]);
    }
    __syncthreads();
    if (g16 == 0) {
        #pragma unroll
        for (int j = 0; j < 8; ++j) red[wv * 128 + c8 + j] = q_[j];
    }
    __syncthreads();
    if (threadIdx.x < 128) {
        const int ch = threadIdx.x;
        atomicAdd(&statsOut[128 + ch], red[ch] + red[128 + ch] + red[256 + ch] + red[384 + ch]);
    }
}

// ---------------- pooling (sorted batch ranges) + readout MLP ----------------

__global__ __launch_bounds__(128) void k_pool(const unsigned short* __restrict__ agg,
                                              const float* __restrict__ bnsc,
                                              const float* __restrict__ bnsh,
                                              const int* __restrict__ gstart,
                                              const float* __restrict__ W1, const float* __restrict__ b1,
                                              const float* __restrict__ W2, const float* __restrict__ b2,
                                              const float* __restrict__ W3, const float* __restrict__ b3,
                                              float* __restrict__ out) {
    __shared__ float mol[128];
    __shared__ float h1s[128];
    const int g = blockIdx.x;
    const int c = threadIdx.x;
    const float sc = bnsc[c], sh = bnsh[c];
    const int v0 = gstart[g], v1 = gstart[g + 1];
    float acc = 0.f;
    for (int v = v0; v < v1; ++v)
        acc += fmaf(bf2f(agg[(size_t)v * 128 + c]), sc, sh);  // last layer: BN, no relu
    mol[c] = acc;
    __syncthreads();
    float a1 = b1[c];
    #pragma unroll 8
    for (int k = 0; k < 128; ++k) a1 = fmaf(mol[k], W1[k * 128 + c], a1);
    h1s[c] = fmaxf(a1, 0.f);
    __syncthreads();
    if (c < 64) {
        float a2 = b2[c];
        #pragma unroll 8
        for (int k = 0; k < 128; ++k) a2 = fmaf(h1s[k], W2[k * 64 + c], a2);
        float p = fmaxf(a2, 0.f) * W3[c];
        #pragma unroll
        for (int o = 32; o > 0; o >>= 1) p += __shfl_down(p, o);
        if (c == 0) out[g] = p + b3[0];
    }
}

// ---------------- launch ----------------

extern "C" void kernel_launch(void* const* d_in, const int* in_sizes, int n_in,
                              void* d_out, int out_size, void* d_ws, size_t ws_size,
                              hipStream_t stream) {
    (void)in_sizes; (void)n_in; (void)out_size; (void)ws_size;
    const float* x     = (const float*)d_in[0];
    const int*   ei    = (const int*)d_in[1];
    const int*   batch = (const int*)d_in[2];
    const float* Wx    = (const float*)d_in[3];
    const float* bx    = (const float*)d_in[4];
    const float* Wg    = (const float*)d_in[5];
    const float* bg    = (const float*)d_in[6];
    const float* gamma = (const float*)d_in[7];
    const float* beta  = (const float*)d_in[8];
    const float* W1    = (const float*)d_in[9];
    const float* b1    = (const float*)d_in[10];
    const float* W2    = (const float*)d_in[11];
    const float* b2    = (const float*)d_in[12];
    const float* W3    = (const float*)d_in[13];
    const float* b3    = (const float*)d_in[14];
    float* out = (float*)d_out;

    char* ws = (char*)d_ws;
    size_t off = 0;
    auto alloc = [&](size_t bytes) -> char* {
        char* p = ws + off;
        off += (bytes + 255) & ~(size_t)255;
        return p;
    };
    unsigned short* aggA   = (unsigned short*)alloc((size_t)NNODES * 128 * 2);
    unsigned short* aggB   = (unsigned short*)alloc((size_t)NNODES * 128 * 2);
    unsigned short* xw     = (unsigned short*)alloc((size_t)NNODES * 128 * 2 + 32768);  // +tail slack
    float*          dinv   = (float*)alloc((size_t)NNODES * 4);
    int*            cnt    = (int*)alloc((size_t)NNODES * 4);
    int*            cursor = (int*)alloc((size_t)NNODES * 4);
    int*            roff   = (int*)alloc((size_t)(NNODES + 1) * 4);
    int2*           cedge  = (int2*)alloc((size_t)(NEDGES + 4) * 8);
    char*           wt     = alloc((size_t)NLAYERS * 32768);
    char*           wxt    = alloc((size_t)16384);
    float*          stats  = (float*)alloc((size_t)NLAYERS * 256 * 4);
    float*          bnsc   = (float*)alloc((size_t)NLAYERS * 128 * 4);
    float*          bnsh   = (float*)alloc((size_t)NLAYERS * 128 * 4);
    int*            gstart = (int*)alloc((size_t)(NGRAPHS + 1) * 4);
    int*            bsum   = (int*)alloc((size_t)1024 * 4);

    const int NB = (NNODES + 255) / 256;   // 782
    const int EB = (NEDGES + 255) / 256;   // 1563
    const int WB = (NLAYERS * 16384 + 8192 + 255) / 256;

    k_init<<<NB, 256, 0, stream>>>(cnt, cursor, stats);
    k_count<<<EB, 256, 0, stream>>>(ei, cnt);
    k_scan1<<<NB, 256, 0, stream>>>(cnt, roff, bsum, batch, gstart);
    k_scan2<<<1, 1024, 0, stream>>>(bsum, NB);
    k_scan3<<<NB, 256, 0, stream>>>(roff, bsum, cnt, dinv);
    k_fill<<<EB, 256, 0, stream>>>(ei, dinv, roff, cursor, cedge);
    k_wtrans<<<WB, 256, 0, stream>>>(Wg, Wx, bx, wt, wxt);
    k_inproj<<<NTILES, 256, 0, stream>>>(x, wxt, aggA);

    unsigned short* cur = aggA;
    unsigned short* nxt = aggB;
    for (int l = 0; l < NLAYERS; ++l) {
        const float* psc = (l > 0) ? (bnsc + (l - 1) * 128) : (const float*)nullptr;
        const float* psh = (l > 0) ? (bnsh + (l - 1) * 128) : (const float*)nullptr;
        k_gemm<<<512, 256, 0, stream>>>(cur, wt + (size_t)l * 32768, xw, psc, psh, l > 0);
        k_agg<<<2048, 256, 0, stream>>>(cur, xw, dinv, roff, cedge, bg + l * 128,
                                        psc, psh, l > 0, nxt, stats + l * 256);
        k_bnfin<<<1, 128, 0, stream>>>(stats + l * 256, gamma + l * 128, beta + l * 128,
                                       bnsc + l * 128, bnsh + l * 128);
        unsigned short* t = cur; cur = nxt; nxt = t;
    }

    k_pool<<<NGRAPHS, 128, 0, stream>>>(cur, bnsc + 4 * 128, bnsh + 4 * 128, gstart,
                                        W1, b1, W2, b2, W3, b3, out);
}